// Round 1
// baseline (36775.156 us; speedup 1.0000x reference)
//
#include <hip/hip_runtime.h>
#include <hip/hip_bf16.h>

// GNN: 5-layer GCN. h_{l+1} = relu(SpMM(adj, mix_l @ W_l)), mix via 0.5*h+0.5*tra.
// Layer 3 computed as (SpMM(m2)) @ W3 (associativity) to scatter at width 500 not 2000.
// Layers 3+4 chunked row-wise to keep workspace at 280 MB.

#define GNN_N 50000
#define CHUNK 10000

// ---------------- tiled fp32 GEMM: C[M,N] = A[M,K] @ B[K,N] ----------------
__global__ __launch_bounds__(256) void gemm_nn(const float* __restrict__ A,
                                               const float* __restrict__ B,
                                               float* __restrict__ C,
                                               int M, int K, int N) {
    __shared__ float As[64][17];   // [row][k]
    __shared__ float Bs[16][65];   // [k][col]
    int tid = threadIdx.x;
    int row0 = blockIdx.y * 64;
    int col0 = blockIdx.x * 64;
    int ty = tid >> 4, tx = tid & 15;
    float acc[4][4] = {};
    for (int k0 = 0; k0 < K; k0 += 16) {
        // load A tile: 64 rows x 16 k (each thread 4 elems)
#pragma unroll
        for (int l = 0; l < 4; ++l) {
            int r = (tid >> 4) + l * 16;
            int kk = tid & 15;
            int gr = row0 + r, gk = k0 + kk;
            As[r][kk] = (gr < M && gk < K) ? A[(size_t)gr * K + gk] : 0.f;
        }
        // load B tile: 16 k x 64 cols
#pragma unroll
        for (int l = 0; l < 4; ++l) {
            int kk = (tid >> 6) + l * 4;
            int c = tid & 63;
            int gk = k0 + kk, gc = col0 + c;
            Bs[kk][c] = (gk < K && gc < N) ? B[(size_t)gk * N + gc] : 0.f;
        }
        __syncthreads();
#pragma unroll
        for (int kk = 0; kk < 16; ++kk) {
            float a[4], b[4];
#pragma unroll
            for (int i = 0; i < 4; ++i) a[i] = As[ty + 16 * i][kk];
#pragma unroll
            for (int j = 0; j < 4; ++j) b[j] = Bs[kk][tx + 16 * j];
#pragma unroll
            for (int i = 0; i < 4; ++i)
#pragma unroll
                for (int j = 0; j < 4; ++j) acc[i][j] += a[i] * b[j];
        }
        __syncthreads();
    }
#pragma unroll
    for (int i = 0; i < 4; ++i) {
        int gr = row0 + ty + 16 * i;
        if (gr >= M) continue;
#pragma unroll
        for (int j = 0; j < 4; ++j) {
            int gc = col0 + tx + 16 * j;
            if (gc < N) C[(size_t)gr * N + gc] = acc[i][j];
        }
    }
}

// ---------------- wave-per-row GEMM, M=10: C[rows,10] = A[rows,K] @ B[K,10] ----------------
__global__ __launch_bounds__(256) void gemm_m10(const float* __restrict__ A,
                                                const float* __restrict__ B,
                                                float* __restrict__ C,
                                                int rows, int K) {
    int wave = (int)((blockIdx.x * 256 + threadIdx.x) >> 6);
    int lane = threadIdx.x & 63;
    if (wave >= rows) return;
    const float* a = A + (size_t)wave * K;
    float acc[10];
#pragma unroll
    for (int j = 0; j < 10; ++j) acc[j] = 0.f;
    for (int k = lane; k < K; k += 64) {
        float av = a[k];
        const float* b = B + (size_t)k * 10;
#pragma unroll
        for (int j = 0; j < 10; ++j) acc[j] += av * b[j];
    }
#pragma unroll
    for (int off = 32; off; off >>= 1) {
#pragma unroll
        for (int j = 0; j < 10; ++j) acc[j] += __shfl_down(acc[j], off, 64);
    }
    if (lane == 0) {
        float* c = C + (size_t)wave * 10;
#pragma unroll
        for (int j = 0; j < 10; ++j) c[j] = acc[j];
    }
}

// ---------------- SpMM scatter, D multiple of 4, D<=512: 128 threads/edge ----------------
__global__ __launch_bounds__(256) void spmm_vec4(const int* __restrict__ rows,
                                                 const int* __restrict__ cols,
                                                 const float* __restrict__ vals,
                                                 const float* __restrict__ S,
                                                 float* __restrict__ O,
                                                 int E, int D) {
    long t = (long)blockIdx.x * 256 + threadIdx.x;
    int e = (int)(t >> 7);
    int ci = (int)(t & 127) * 4;
    if (e >= E || ci >= D) return;
    float v = vals[e];
    const float* srow = S + (size_t)cols[e] * D + ci;
    float* orow = O + (size_t)rows[e] * D + ci;
    float4 s = *(const float4*)srow;
    atomicAdd(orow + 0, v * s.x);
    atomicAdd(orow + 1, v * s.y);
    atomicAdd(orow + 2, v * s.z);
    atomicAdd(orow + 3, v * s.w);
}

// ---------------- SpMM scatter, small D (<=16), scalar: 16 threads/edge ----------------
__global__ __launch_bounds__(256) void spmm_small(const int* __restrict__ rows,
                                                  const int* __restrict__ cols,
                                                  const float* __restrict__ vals,
                                                  const float* __restrict__ S,
                                                  float* __restrict__ O,
                                                  int E, int D) {
    long t = (long)blockIdx.x * 256 + threadIdx.x;
    int e = (int)(t >> 4);
    int c = (int)(t & 15);
    if (e >= E || c >= D) return;
    atomicAdd(O + (size_t)rows[e] * D + c, vals[e] * S[(size_t)cols[e] * D + c]);
}

// ---------------- elementwise: h = 0.5*relu(h) + 0.5*t (float4) ----------------
__global__ __launch_bounds__(256) void relu_mix(float* __restrict__ h,
                                                const float* __restrict__ t,
                                                long n4) {
    long i = (long)blockIdx.x * 256 + threadIdx.x;
    if (i >= n4) return;
    float4 hv = ((const float4*)h)[i];
    float4 tv = ((const float4*)t)[i];
    hv.x = 0.5f * fmaxf(hv.x, 0.f) + 0.5f * tv.x;
    hv.y = 0.5f * fmaxf(hv.y, 0.f) + 0.5f * tv.y;
    hv.z = 0.5f * fmaxf(hv.z, 0.f) + 0.5f * tv.z;
    hv.w = 0.5f * fmaxf(hv.w, 0.f) + 0.5f * tv.w;
    ((float4*)h)[i] = hv;
}

extern "C" void kernel_launch(void* const* d_in, const int* in_sizes, int n_in,
                              void* d_out, int out_size, void* d_ws, size_t ws_size,
                              hipStream_t stream) {
    const float* x    = (const float*)d_in[0];
    const int*   ar   = (const int*)d_in[1];
    const int*   ac   = (const int*)d_in[2];
    const float* av   = (const float*)d_in[3];
    const float* tra1 = (const float*)d_in[4];
    const float* tra2 = (const float*)d_in[5];
    const float* tra3 = (const float*)d_in[6];
    const float* z    = (const float*)d_in[7];
    const float* W1   = (const float*)d_in[8];
    const float* W2   = (const float*)d_in[9];
    const float* W3   = (const float*)d_in[10];
    const float* W4   = (const float*)d_in[11];
    const float* W5   = (const float*)d_in[12];

    const int E = in_sizes[1];
    const int N = in_sizes[7] / 10;   // 50000

    float* A  = (float*)d_ws;                   // [N,500]
    float* Bb = A + (size_t)N * 500;            // [N,500]
    float* Cc = Bb + (size_t)N * 500;           // [CHUNK,2000]
    float* out = (float*)d_out;

    dim3 blk(256);
    int spmm500_blocks = (int)(((long)E * 128 + 255) / 256);
    int spmm10_blocks  = (int)(((long)E * 16 + 255) / 256);

    // ---- Layer 1: support = x @ W1 [N,512]x[512,500] -> Bb
    {
        dim3 g((500 + 63) / 64, (N + 63) / 64);
        gemm_nn<<<g, blk, 0, stream>>>(x, W1, Bb, N, 512, 500);
    }
    hipMemsetAsync(A, 0, (size_t)N * 500 * sizeof(float), stream);
    spmm_vec4<<<spmm500_blocks, blk, 0, stream>>>(ar, ac, av, Bb, A, E, 500);
    relu_mix<<<(int)(((long)N * 500 / 4 + 255) / 256), blk, 0, stream>>>(A, tra1, (long)N * 500 / 4);

    // ---- Layer 2: support = m1 @ W2 [N,500]x[500,500] -> Bb
    {
        dim3 g((500 + 63) / 64, (N + 63) / 64);
        gemm_nn<<<g, blk, 0, stream>>>(A, W2, Bb, N, 500, 500);
    }
    hipMemsetAsync(A, 0, (size_t)N * 500 * sizeof(float), stream);
    spmm_vec4<<<spmm500_blocks, blk, 0, stream>>>(ar, ac, av, Bb, A, E, 500);
    relu_mix<<<(int)(((long)N * 500 / 4 + 255) / 256), blk, 0, stream>>>(A, tra2, (long)N * 500 / 4);

    // ---- Layer 3 (spmm-first): g = SpMM(m2) -> Bb ; then chunked [g@W3, relu+mix tra3, @W4]
    hipMemsetAsync(Bb, 0, (size_t)N * 500 * sizeof(float), stream);
    spmm_vec4<<<spmm500_blocks, blk, 0, stream>>>(ar, ac, av, A, Bb, E, 500);

    for (int c = 0; c < N / CHUNK; ++c) {
        int r0 = c * CHUNK;
        dim3 g((2000 + 63) / 64, (CHUNK + 63) / 64);
        gemm_nn<<<g, blk, 0, stream>>>(Bb + (size_t)r0 * 500, W3, Cc, CHUNK, 500, 2000);
        relu_mix<<<(int)(((long)CHUNK * 2000 / 4 + 255) / 256), blk, 0, stream>>>(
            Cc, tra3 + (size_t)r0 * 2000, (long)CHUNK * 2000 / 4);
        gemm_m10<<<(CHUNK + 3) / 4, blk, 0, stream>>>(Cc, W4, A + (size_t)r0 * 10, CHUNK, 2000);
    }

    // ---- Layer 4 spmm: Bb[:,0:10] = SpMM(support4 in A), relu+mix z
    hipMemsetAsync(Bb, 0, (size_t)N * 10 * sizeof(float), stream);
    spmm_small<<<spmm10_blocks, blk, 0, stream>>>(ar, ac, av, A, Bb, E, 10);
    relu_mix<<<(int)(((long)N * 10 / 4 + 255) / 256), blk, 0, stream>>>(Bb, z, (long)N * 10 / 4);

    // ---- Layer 5: support = m4 @ W5 -> A ; out = SpMM(support), no relu
    gemm_m10<<<(N + 3) / 4, blk, 0, stream>>>(Bb, W5, A, N, 10);
    hipMemsetAsync(out, 0, (size_t)N * 10 * sizeof(float), stream);
    spmm_small<<<spmm10_blocks, blk, 0, stream>>>(ar, ac, av, A, out, E, 10);
}

// Round 2
// 5500.227 us; speedup vs baseline: 6.6861x; 6.6861x over previous
//
#include <hip/hip_runtime.h>
#include <hip/hip_bf16.h>

// GNN: 5-layer GCN. h_{l+1} = relu(SpMM(adj, mix_l @ W_l)), mix = 0.5*h+0.5*tra.
// Round 2: SpMM via on-device CSR build (counting sort) + gather (wave/row),
// replacing 800M-atomic scatter (was 3x10.9ms). relu+mix fused into SpMM epilogue.
// Layer 3 computed as (SpMM(m2)) @ W3 (associativity). Layers 3+4 chunked (5000 rows).

#define GNN_N 50000
#define CHUNK 5000
#define SCAN_CHUNK 512

// ---------------- tiled fp32 GEMM: C[M,N] = A[M,K] @ B[K,N] ----------------
__global__ __launch_bounds__(256) void gemm_nn(const float* __restrict__ A,
                                               const float* __restrict__ B,
                                               float* __restrict__ C,
                                               int M, int K, int N) {
    __shared__ float As[64][17];
    __shared__ float Bs[16][65];
    int tid = threadIdx.x;
    int row0 = blockIdx.y * 64;
    int col0 = blockIdx.x * 64;
    int ty = tid >> 4, tx = tid & 15;
    float acc[4][4] = {};
    for (int k0 = 0; k0 < K; k0 += 16) {
#pragma unroll
        for (int l = 0; l < 4; ++l) {
            int r = (tid >> 4) + l * 16;
            int kk = tid & 15;
            int gr = row0 + r, gk = k0 + kk;
            As[r][kk] = (gr < M && gk < K) ? A[(size_t)gr * K + gk] : 0.f;
        }
#pragma unroll
        for (int l = 0; l < 4; ++l) {
            int kk = (tid >> 6) + l * 4;
            int c = tid & 63;
            int gk = k0 + kk, gc = col0 + c;
            Bs[kk][c] = (gk < K && gc < N) ? B[(size_t)gk * N + gc] : 0.f;
        }
        __syncthreads();
#pragma unroll
        for (int kk = 0; kk < 16; ++kk) {
            float a[4], b[4];
#pragma unroll
            for (int i = 0; i < 4; ++i) a[i] = As[ty + 16 * i][kk];
#pragma unroll
            for (int j = 0; j < 4; ++j) b[j] = Bs[kk][tx + 16 * j];
#pragma unroll
            for (int i = 0; i < 4; ++i)
#pragma unroll
                for (int j = 0; j < 4; ++j) acc[i][j] += a[i] * b[j];
        }
        __syncthreads();
    }
#pragma unroll
    for (int i = 0; i < 4; ++i) {
        int gr = row0 + ty + 16 * i;
        if (gr >= M) continue;
#pragma unroll
        for (int j = 0; j < 4; ++j) {
            int gc = col0 + tx + 16 * j;
            if (gc < N) C[(size_t)gr * N + gc] = acc[i][j];
        }
    }
}

// ---------------- wave-per-row GEMM, 10 outputs: C[rows,10] = A[rows,K] @ B[K,10] ----
__global__ __launch_bounds__(256) void gemm_m10(const float* __restrict__ A,
                                                const float* __restrict__ B,
                                                float* __restrict__ C,
                                                int rows, int K) {
    int wave = (int)((blockIdx.x * 256 + threadIdx.x) >> 6);
    int lane = threadIdx.x & 63;
    if (wave >= rows) return;
    const float* a = A + (size_t)wave * K;
    float acc[10];
#pragma unroll
    for (int j = 0; j < 10; ++j) acc[j] = 0.f;
    for (int k = lane; k < K; k += 64) {
        float av = a[k];
        const float* b = B + (size_t)k * 10;
#pragma unroll
        for (int j = 0; j < 10; ++j) acc[j] += av * b[j];
    }
#pragma unroll
    for (int off = 32; off; off >>= 1) {
#pragma unroll
        for (int j = 0; j < 10; ++j) acc[j] += __shfl_down(acc[j], off, 64);
    }
    if (lane == 0) {
        float* c = C + (size_t)wave * 10;
#pragma unroll
        for (int j = 0; j < 10; ++j) c[j] = acc[j];
    }
}

// ---------------- CSR build: count / scan / fill ----------------
__global__ __launch_bounds__(256) void csr_count(const int* __restrict__ rows,
                                                 int* __restrict__ cnt, int E) {
    int e = blockIdx.x * 256 + threadIdx.x;
    if (e < E) atomicAdd(&cnt[rows[e]], 1);
}

__global__ __launch_bounds__(256) void scan1(const int* __restrict__ cnt,
                                             int* __restrict__ csum, int n) {
    __shared__ int red[256];
    int base = blockIdx.x * SCAN_CHUNK;
    int t = threadIdx.x;
    int s = 0;
    if (base + t < n) s += cnt[base + t];
    if (base + t + 256 < n) s += cnt[base + t + 256];
    red[t] = s;
    __syncthreads();
    for (int off = 128; off; off >>= 1) {
        if (t < off) red[t] += red[t + off];
        __syncthreads();
    }
    if (t == 0) csum[blockIdx.x] = red[0];
}

__global__ void scan2(int* csum, int nch) {
    if (threadIdx.x == 0 && blockIdx.x == 0) {
        int acc = 0;
        for (int i = 0; i < nch; ++i) { int v = csum[i]; csum[i] = acc; acc += v; }
    }
}

__global__ __launch_bounds__(256) void scan3(const int* __restrict__ cnt,
                                             const int* __restrict__ csum,
                                             int* __restrict__ rowptr, int n, int E) {
    __shared__ int sm[SCAN_CHUNK];
    int base = blockIdx.x * SCAN_CHUNK;
    int t = threadIdx.x;
    for (int i = t; i < SCAN_CHUNK; i += 256) sm[i] = (base + i < n) ? cnt[base + i] : 0;
    __syncthreads();
    for (int off = 1; off < SCAN_CHUNK; off <<= 1) {
        int i0 = t, i1 = t + 256;
        int v0 = (i0 >= off) ? sm[i0 - off] : 0;
        int v1 = (i1 >= off) ? sm[i1 - off] : 0;
        __syncthreads();
        sm[i0] += v0;
        sm[i1] += v1;
        __syncthreads();
    }
    int off0 = csum[blockIdx.x];
    for (int i = t; i < SCAN_CHUNK; i += 256)
        if (base + i < n) rowptr[base + i] = off0 + (i ? sm[i - 1] : 0);
    if (blockIdx.x == 0 && t == 0) rowptr[n] = E;
}

__global__ __launch_bounds__(256) void csr_fill(const int* __restrict__ rows,
                                                const int* __restrict__ cols,
                                                const float* __restrict__ vals,
                                                int* __restrict__ cur,
                                                int* __restrict__ ecols,
                                                float* __restrict__ evals, int E) {
    int e = blockIdx.x * 256 + threadIdx.x;
    if (e >= E) return;
    int p = atomicAdd(&cur[rows[e]], 1);
    ecols[p] = cols[e];
    evals[p] = vals[e];
}

// ---------------- SpMM gather, D=500: one wave per row, acc in registers ------------
__global__ __launch_bounds__(256) void spmm_csr500(const int* __restrict__ rowptr,
                                                   const int* __restrict__ ecols,
                                                   const float* __restrict__ evals,
                                                   const float* __restrict__ S,
                                                   const float* __restrict__ T,
                                                   float* __restrict__ O,
                                                   int nrows, int domix) {
    int wid = (int)((blockIdx.x * 256 + threadIdx.x) >> 6);
    int lane = threadIdx.x & 63;
    if (wid >= nrows) return;
    int beg = rowptr[wid], end = rowptr[wid + 1];
    const bool hi = lane < 61;   // 125 float4 per row; lane + [0,64)
    float4 acc0 = {0.f, 0.f, 0.f, 0.f}, acc1 = {0.f, 0.f, 0.f, 0.f};
    int e = beg;
    for (; e + 1 < end; e += 2) {
        int ca = ecols[e], cb = ecols[e + 1];
        float va = evals[e], vb = evals[e + 1];
        const float4* sa = (const float4*)(S + (size_t)ca * 500);
        const float4* sb = (const float4*)(S + (size_t)cb * 500);
        float4 a0 = sa[lane];
        float4 b0 = sb[lane];
        acc0.x += va * a0.x + vb * b0.x;
        acc0.y += va * a0.y + vb * b0.y;
        acc0.z += va * a0.z + vb * b0.z;
        acc0.w += va * a0.w + vb * b0.w;
        if (hi) {
            float4 a1 = sa[lane + 64];
            float4 b1 = sb[lane + 64];
            acc1.x += va * a1.x + vb * b1.x;
            acc1.y += va * a1.y + vb * b1.y;
            acc1.z += va * a1.z + vb * b1.z;
            acc1.w += va * a1.w + vb * b1.w;
        }
    }
    if (e < end) {
        int ca = ecols[e];
        float va = evals[e];
        const float4* sa = (const float4*)(S + (size_t)ca * 500);
        float4 a0 = sa[lane];
        acc0.x += va * a0.x; acc0.y += va * a0.y;
        acc0.z += va * a0.z; acc0.w += va * a0.w;
        if (hi) {
            float4 a1 = sa[lane + 64];
            acc1.x += va * a1.x; acc1.y += va * a1.y;
            acc1.z += va * a1.z; acc1.w += va * a1.w;
        }
    }
    float4* o4 = (float4*)(O + (size_t)wid * 500);
    if (domix) {
        const float4* t4 = (const float4*)(T + (size_t)wid * 500);
        float4 tv = t4[lane];
        acc0.x = 0.5f * fmaxf(acc0.x, 0.f) + 0.5f * tv.x;
        acc0.y = 0.5f * fmaxf(acc0.y, 0.f) + 0.5f * tv.y;
        acc0.z = 0.5f * fmaxf(acc0.z, 0.f) + 0.5f * tv.z;
        acc0.w = 0.5f * fmaxf(acc0.w, 0.f) + 0.5f * tv.w;
        o4[lane] = acc0;
        if (hi) {
            float4 tv1 = t4[lane + 64];
            acc1.x = 0.5f * fmaxf(acc1.x, 0.f) + 0.5f * tv1.x;
            acc1.y = 0.5f * fmaxf(acc1.y, 0.f) + 0.5f * tv1.y;
            acc1.z = 0.5f * fmaxf(acc1.z, 0.f) + 0.5f * tv1.z;
            acc1.w = 0.5f * fmaxf(acc1.w, 0.f) + 0.5f * tv1.w;
            o4[lane + 64] = acc1;
        }
    } else {
        o4[lane] = acc0;
        if (hi) o4[lane + 64] = acc1;
    }
}

// ---------------- SpMM gather, D=10: 16-thread group per row ----------------
__global__ __launch_bounds__(256) void spmm_csr10(const int* __restrict__ rowptr,
                                                  const int* __restrict__ ecols,
                                                  const float* __restrict__ evals,
                                                  const float* __restrict__ S,
                                                  const float* __restrict__ T,
                                                  float* __restrict__ O,
                                                  int nrows, int domix) {
    int g = (int)((blockIdx.x * 256 + threadIdx.x) >> 4);
    int t = threadIdx.x & 15;
    if (g >= nrows || t >= 10) return;
    int beg = rowptr[g], end = rowptr[g + 1];
    float acc = 0.f;
    for (int e = beg; e < end; ++e)
        acc += evals[e] * S[(size_t)ecols[e] * 10 + t];
    if (domix) acc = 0.5f * fmaxf(acc, 0.f) + 0.5f * T[(size_t)g * 10 + t];
    O[(size_t)g * 10 + t] = acc;
}

// ---------------- elementwise: h = 0.5*relu(h) + 0.5*t (float4) ----------------
__global__ __launch_bounds__(256) void relu_mix(float* __restrict__ h,
                                                const float* __restrict__ t,
                                                long n4) {
    long i = (long)blockIdx.x * 256 + threadIdx.x;
    if (i >= n4) return;
    float4 hv = ((const float4*)h)[i];
    float4 tv = ((const float4*)t)[i];
    hv.x = 0.5f * fmaxf(hv.x, 0.f) + 0.5f * tv.x;
    hv.y = 0.5f * fmaxf(hv.y, 0.f) + 0.5f * tv.y;
    hv.z = 0.5f * fmaxf(hv.z, 0.f) + 0.5f * tv.z;
    hv.w = 0.5f * fmaxf(hv.w, 0.f) + 0.5f * tv.w;
    ((float4*)h)[i] = hv;
}

extern "C" void kernel_launch(void* const* d_in, const int* in_sizes, int n_in,
                              void* d_out, int out_size, void* d_ws, size_t ws_size,
                              hipStream_t stream) {
    const float* x    = (const float*)d_in[0];
    const int*   ar   = (const int*)d_in[1];
    const int*   ac   = (const int*)d_in[2];
    const float* av   = (const float*)d_in[3];
    const float* tra1 = (const float*)d_in[4];
    const float* tra2 = (const float*)d_in[5];
    const float* tra3 = (const float*)d_in[6];
    const float* z    = (const float*)d_in[7];
    const float* W1   = (const float*)d_in[8];
    const float* W2   = (const float*)d_in[9];
    const float* W3   = (const float*)d_in[10];
    const float* W4   = (const float*)d_in[11];
    const float* W5   = (const float*)d_in[12];

    const int E = in_sizes[1];
    const int N = in_sizes[7] / 10;   // 50000
    const int NCH = (N + SCAN_CHUNK - 1) / SCAN_CHUNK;

    float* A      = (float*)d_ws;                     // [N,500]
    float* Bb     = A + (size_t)N * 500;              // [N,500]
    float* Cc     = Bb + (size_t)N * 500;             // [CHUNK,2000]
    int*   ecols  = (int*)(Cc + (size_t)CHUNK * 2000);// [E]
    float* evals  = (float*)(ecols + E);              // [E]
    int*   rowptr = (int*)(evals + E);                // [N+1]
    int*   cnt    = rowptr + (N + 1);                 // [N]
    int*   csum   = cnt + N;                          // [NCH]
    float* out    = (float*)d_out;

    dim3 blk(256);

    // ---- CSR build (counting sort) ----
    hipMemsetAsync(cnt, 0, (size_t)N * sizeof(int), stream);
    csr_count<<<(E + 255) / 256, blk, 0, stream>>>(ar, cnt, E);
    scan1<<<NCH, blk, 0, stream>>>(cnt, csum, N);
    scan2<<<1, 64, 0, stream>>>(csum, NCH);
    scan3<<<NCH, blk, 0, stream>>>(cnt, csum, rowptr, N, E);
    hipMemcpyAsync(cnt, rowptr, (size_t)N * sizeof(int), hipMemcpyDeviceToDevice, stream);
    csr_fill<<<(E + 255) / 256, blk, 0, stream>>>(ar, ac, av, cnt, ecols, evals, E);

    const int spmm500_blocks = (N * 64 + 255) / 256;   // one wave per row
    const int spmm10_blocks  = (N * 16 + 255) / 256;   // 16 threads per row

    // ---- Layer 1: support = x @ W1 -> Bb ; m1 = mix(relu(spmm), tra1) -> A
    {
        dim3 g((500 + 63) / 64, (N + 63) / 64);
        gemm_nn<<<g, blk, 0, stream>>>(x, W1, Bb, N, 512, 500);
    }
    spmm_csr500<<<spmm500_blocks, blk, 0, stream>>>(rowptr, ecols, evals, Bb, tra1, A, N, 1);

    // ---- Layer 2: support = m1 @ W2 -> Bb ; m2 = mix(relu(spmm), tra2) -> A
    {
        dim3 g((500 + 63) / 64, (N + 63) / 64);
        gemm_nn<<<g, blk, 0, stream>>>(A, W2, Bb, N, 500, 500);
    }
    spmm_csr500<<<spmm500_blocks, blk, 0, stream>>>(rowptr, ecols, evals, Bb, tra2, A, N, 1);

    // ---- Layer 3 (spmm-first): g = SpMM(m2) -> Bb (raw); chunked g@W3, relu+mix, @W4 -> A[:,10]
    spmm_csr500<<<spmm500_blocks, blk, 0, stream>>>(rowptr, ecols, evals, A, nullptr, Bb, N, 0);

    for (int c = 0; c < N / CHUNK; ++c) {
        int r0 = c * CHUNK;
        dim3 g((2000 + 63) / 64, (CHUNK + 63) / 64);
        gemm_nn<<<g, blk, 0, stream>>>(Bb + (size_t)r0 * 500, W3, Cc, CHUNK, 500, 2000);
        relu_mix<<<(int)(((long)CHUNK * 2000 / 4 + 255) / 256), blk, 0, stream>>>(
            Cc, tra3 + (size_t)r0 * 2000, (long)CHUNK * 2000 / 4);
        gemm_m10<<<(CHUNK * 64 + 255) / 256, blk, 0, stream>>>(Cc, W4, A + (size_t)r0 * 10, CHUNK, 2000);
    }

    // ---- Layer 4: h4 = spmm(A[:,10]); m4 = mix(relu, z) -> Bb[:,10]
    spmm_csr10<<<spmm10_blocks, blk, 0, stream>>>(rowptr, ecols, evals, A, z, Bb, N, 1);

    // ---- Layer 5: support = m4 @ W5 -> A[:,10] ; out = spmm (raw)
    gemm_m10<<<(N * 64 + 255) / 256, blk, 0, stream>>>(Bb, W5, A, N, 10);
    spmm_csr10<<<spmm10_blocks, blk, 0, stream>>>(rowptr, ecols, evals, A, nullptr, out, N, 0);
}

// Round 3
// 2826.239 us; speedup vs baseline: 13.0120x; 1.9461x over previous
//
#include <hip/hip_runtime.h>
#include <hip/hip_bf16.h>

// GNN: 5-layer GCN. Round 3: bf16 MFMA GEMM (m97-style 128x128 tile, global_load_lds,
// B stored transposed+padded, K padded to 512). SpMM epilogues emit bf16 directly;
// GEMM3 epilogue fuses relu+mix(tra3). SpMM via CSR gather (round 2).

#define CHUNK 10000
#define SCAN_CHUNK 512
#define BM 128
#define BN 128
#define BK 64

typedef __attribute__((ext_vector_type(4))) float f32x4;
typedef __attribute__((ext_vector_type(8))) __bf16 bf16x8;
typedef __attribute__((ext_vector_type(8))) short s16x8;

__device__ __forceinline__ bf16x8 as_bf(s16x8 v) { union { s16x8 s; bf16x8 b; } u; u.s = v; return u.b; }
__device__ __forceinline__ ushort f2bf(float f) {
    uint u = __float_as_uint(f);
    return (ushort)((u + 0x7FFFu + ((u >> 16) & 1u)) >> 16);   // RNE
}

#define GLL16(g, l)                                                                 \
    __builtin_amdgcn_global_load_lds((const __attribute__((address_space(1))) void*)(g), \
                                     (__attribute__((address_space(3))) void*)(l), 16, 0, 0)

// ---------------- bf16 MFMA GEMM: C[M,Nreal] = A[M,512]bf16 @ Bt[Npad,512]bf16^T ----
// Optional epilogue: C = 0.5*relu(C) + 0.5*T  (T stride Nreal)
__global__ __launch_bounds__(256) void gemm_bf16(const ushort* __restrict__ A,
                                                 const ushort* __restrict__ Bt,
                                                 float* __restrict__ C,
                                                 const float* __restrict__ T,
                                                 int M, int Nreal, int domix) {
    __shared__ ushort As[BM * BK];   // [row][k] linear
    __shared__ ushort Bs[BN * BK];   // [col][k] linear
    int tid = threadIdx.x;
    int w = tid >> 6, l = tid & 63;
    int row0 = blockIdx.y * BM, col0 = blockIdx.x * BN;
    int wr = (w >> 1) * 64, wc = (w & 1) * 64;

    f32x4 acc[4][4] = {};

    int arow_off = w * 8 + (l >> 3);          // within-tile staging row
    int acol = (l & 7) * 8;                   // k elems within BK

    for (int k0 = 0; k0 < 512; k0 += BK) {
        __syncthreads();
#pragma unroll
        for (int i = 0; i < 4; ++i) {
            int ar = row0 + arow_off + i * 32;
            if (ar >= M) ar = M - 1;          // clamp (dup row; discarded by C guard)
            const ushort* ga = A + (size_t)ar * 512 + k0 + acol;
            GLL16(ga, &As[(w * 8 + i * 32) * BK]);
            const ushort* gb = Bt + (size_t)(col0 + arow_off + i * 32) * 512 + k0 + acol;
            GLL16(gb, &Bs[(w * 8 + i * 32) * BK]);
        }
        __syncthreads();
#pragma unroll
        for (int s = 0; s < 2; ++s) {
            int kb = s * 32 + (l >> 4) * 8;
            bf16x8 af[4], bfr[4];
#pragma unroll
            for (int m = 0; m < 4; ++m)
                af[m] = as_bf(*(const s16x8*)&As[(wr + m * 16 + (l & 15)) * BK + kb]);
#pragma unroll
            for (int n = 0; n < 4; ++n)
                bfr[n] = as_bf(*(const s16x8*)&Bs[(wc + n * 16 + (l & 15)) * BK + kb]);
#pragma unroll
            for (int m = 0; m < 4; ++m)
#pragma unroll
                for (int n = 0; n < 4; ++n)
                    acc[m][n] = __builtin_amdgcn_mfma_f32_16x16x32_bf16(af[m], bfr[n], acc[m][n], 0, 0, 0);
        }
    }
    int crow = (l >> 4) * 4;
    int ccol = l & 15;
#pragma unroll
    for (int m = 0; m < 4; ++m)
#pragma unroll
        for (int n = 0; n < 4; ++n) {
            int gc = col0 + wc + n * 16 + ccol;
            if (gc >= Nreal) continue;
#pragma unroll
            for (int r = 0; r < 4; ++r) {
                int gr = row0 + wr + m * 16 + crow + r;
                if (gr >= M) continue;
                float v = acc[m][n][r];
                size_t idx = (size_t)gr * Nreal + gc;
                if (domix) v = 0.5f * fmaxf(v, 0.f) + 0.5f * T[idx];
                C[idx] = v;
            }
        }
}

// ---------------- wave-per-row GEMM, 10 outputs (fp32) ----------------
__global__ __launch_bounds__(256) void gemm_m10(const float* __restrict__ A,
                                                const float* __restrict__ B,
                                                float* __restrict__ C,
                                                int rows, int K) {
    int wave = (int)((blockIdx.x * 256 + threadIdx.x) >> 6);
    int lane = threadIdx.x & 63;
    if (wave >= rows) return;
    const float* a = A + (size_t)wave * K;
    float acc[10];
#pragma unroll
    for (int j = 0; j < 10; ++j) acc[j] = 0.f;
    for (int k = lane; k < K; k += 64) {
        float av = a[k];
        const float* b = B + (size_t)k * 10;
#pragma unroll
        for (int j = 0; j < 10; ++j) acc[j] += av * b[j];
    }
#pragma unroll
    for (int off = 32; off; off >>= 1) {
#pragma unroll
        for (int j = 0; j < 10; ++j) acc[j] += __shfl_down(acc[j], off, 64);
    }
    if (lane == 0) {
        float* c = C + (size_t)wave * 10;
#pragma unroll
        for (int j = 0; j < 10; ++j) c[j] = acc[j];
    }
}

// ---------------- conversions ----------------
__global__ __launch_bounds__(256) void cvt4(const float* __restrict__ s,
                                            ushort* __restrict__ d, long n4) {
    long i = (long)blockIdx.x * 256 + threadIdx.x;
    if (i >= n4) return;
    float4 v = ((const float4*)s)[i];
    ushort4 o = { f2bf(v.x), f2bf(v.y), f2bf(v.z), f2bf(v.w) };
    ((ushort4*)d)[i] = o;
}

// Wt[n][k] (Npad x 512) = bf16(W[k][n]), zero-padded
__global__ __launch_bounds__(256) void cvt_wt(const float* __restrict__ W,
                                              ushort* __restrict__ Wt,
                                              int Ksrc, int Nsrc, int Npad) {
    int i = blockIdx.x * 256 + threadIdx.x;
    if (i >= Npad * 512) return;
    int n = i >> 9, k = i & 511;
    float v = (k < Ksrc && n < Nsrc) ? W[(size_t)k * Nsrc + n] : 0.f;
    Wt[i] = f2bf(v);
}

// ---------------- CSR build: count / scan / fill ----------------
__global__ __launch_bounds__(256) void csr_count(const int* __restrict__ rows,
                                                 int* __restrict__ cnt, int E) {
    int e = blockIdx.x * 256 + threadIdx.x;
    if (e < E) atomicAdd(&cnt[rows[e]], 1);
}

__global__ __launch_bounds__(256) void scan1(const int* __restrict__ cnt,
                                             int* __restrict__ csum, int n) {
    __shared__ int red[256];
    int base = blockIdx.x * SCAN_CHUNK;
    int t = threadIdx.x;
    int s = 0;
    if (base + t < n) s += cnt[base + t];
    if (base + t + 256 < n) s += cnt[base + t + 256];
    red[t] = s;
    __syncthreads();
    for (int off = 128; off; off >>= 1) {
        if (t < off) red[t] += red[t + off];
        __syncthreads();
    }
    if (t == 0) csum[blockIdx.x] = red[0];
}

__global__ void scan2(int* csum, int nch) {
    if (threadIdx.x == 0 && blockIdx.x == 0) {
        int acc = 0;
        for (int i = 0; i < nch; ++i) { int v = csum[i]; csum[i] = acc; acc += v; }
    }
}

__global__ __launch_bounds__(256) void scan3(const int* __restrict__ cnt,
                                             const int* __restrict__ csum,
                                             int* __restrict__ rowptr, int n, int E) {
    __shared__ int sm[SCAN_CHUNK];
    int base = blockIdx.x * SCAN_CHUNK;
    int t = threadIdx.x;
    for (int i = t; i < SCAN_CHUNK; i += 256) sm[i] = (base + i < n) ? cnt[base + i] : 0;
    __syncthreads();
    for (int off = 1; off < SCAN_CHUNK; off <<= 1) {
        int i0 = t, i1 = t + 256;
        int v0 = (i0 >= off) ? sm[i0 - off] : 0;
        int v1 = (i1 >= off) ? sm[i1 - off] : 0;
        __syncthreads();
        sm[i0] += v0;
        sm[i1] += v1;
        __syncthreads();
    }
    int off0 = csum[blockIdx.x];
    for (int i = t; i < SCAN_CHUNK; i += 256)
        if (base + i < n) rowptr[base + i] = off0 + (i ? sm[i - 1] : 0);
    if (blockIdx.x == 0 && t == 0) rowptr[n] = E;
}

__global__ __launch_bounds__(256) void csr_fill(const int* __restrict__ rows,
                                                const int* __restrict__ cols,
                                                const float* __restrict__ vals,
                                                int* __restrict__ cur,
                                                int* __restrict__ ecols,
                                                float* __restrict__ evals, int E) {
    int e = blockIdx.x * 256 + threadIdx.x;
    if (e >= E) return;
    int p = atomicAdd(&cur[rows[e]], 1);
    ecols[p] = cols[e];
    evals[p] = vals[e];
}

// ---------------- SpMM gather, D=500 src stride: wave per row ----------------
// mode: 0 = f32 raw, 1 = f32 mix, 2 = bf16 mix (dst stride 512, pad zeros), 3 = bf16 raw
__global__ __launch_bounds__(256) void spmm_csr500(const int* __restrict__ rowptr,
                                                   const int* __restrict__ ecols,
                                                   const float* __restrict__ evals,
                                                   const float* __restrict__ S,
                                                   const float* __restrict__ T,
                                                   float* __restrict__ Of,
                                                   ushort* __restrict__ Ob,
                                                   int nrows, int mode) {
    int wid = (int)((blockIdx.x * 256 + threadIdx.x) >> 6);
    int lane = threadIdx.x & 63;
    if (wid >= nrows) return;
    int beg = rowptr[wid], end = rowptr[wid + 1];
    const bool hi = lane < 61;   // 125 float4 per 500-float row
    float4 acc0 = {0.f, 0.f, 0.f, 0.f}, acc1 = {0.f, 0.f, 0.f, 0.f};
    int e = beg;
    for (; e + 1 < end; e += 2) {
        int ca = ecols[e], cb = ecols[e + 1];
        float va = evals[e], vb = evals[e + 1];
        const float4* sa = (const float4*)(S + (size_t)ca * 500);
        const float4* sb = (const float4*)(S + (size_t)cb * 500);
        float4 a0 = sa[lane], b0 = sb[lane];
        acc0.x += va * a0.x + vb * b0.x;
        acc0.y += va * a0.y + vb * b0.y;
        acc0.z += va * a0.z + vb * b0.z;
        acc0.w += va * a0.w + vb * b0.w;
        if (hi) {
            float4 a1 = sa[lane + 64], b1 = sb[lane + 64];
            acc1.x += va * a1.x + vb * b1.x;
            acc1.y += va * a1.y + vb * b1.y;
            acc1.z += va * a1.z + vb * b1.z;
            acc1.w += va * a1.w + vb * b1.w;
        }
    }
    if (e < end) {
        int ca = ecols[e];
        float va = evals[e];
        const float4* sa = (const float4*)(S + (size_t)ca * 500);
        float4 a0 = sa[lane];
        acc0.x += va * a0.x; acc0.y += va * a0.y;
        acc0.z += va * a0.z; acc0.w += va * a0.w;
        if (hi) {
            float4 a1 = sa[lane + 64];
            acc1.x += va * a1.x; acc1.y += va * a1.y;
            acc1.z += va * a1.z; acc1.w += va * a1.w;
        }
    }
    const bool domix = (mode == 1) | (mode == 2);
    if (domix) {
        const float4* t4 = (const float4*)(T + (size_t)wid * 500);
        float4 tv = t4[lane];
        acc0.x = 0.5f * fmaxf(acc0.x, 0.f) + 0.5f * tv.x;
        acc0.y = 0.5f * fmaxf(acc0.y, 0.f) + 0.5f * tv.y;
        acc0.z = 0.5f * fmaxf(acc0.z, 0.f) + 0.5f * tv.z;
        acc0.w = 0.5f * fmaxf(acc0.w, 0.f) + 0.5f * tv.w;
        if (hi) {
            float4 tv1 = t4[lane + 64];
            acc1.x = 0.5f * fmaxf(acc1.x, 0.f) + 0.5f * tv1.x;
            acc1.y = 0.5f * fmaxf(acc1.y, 0.f) + 0.5f * tv1.y;
            acc1.z = 0.5f * fmaxf(acc1.z, 0.f) + 0.5f * tv1.z;
            acc1.w = 0.5f * fmaxf(acc1.w, 0.f) + 0.5f * tv1.w;
        }
    }
    if (mode <= 1) {
        float4* o4 = (float4*)(Of + (size_t)wid * 500);
        o4[lane] = acc0;
        if (hi) o4[lane + 64] = acc1;
    } else {
        ushort4* ob = (ushort4*)(Ob + (size_t)wid * 512);
        ushort4 p0 = { f2bf(acc0.x), f2bf(acc0.y), f2bf(acc0.z), f2bf(acc0.w) };
        ob[lane] = p0;
        ushort4 p1 = {0, 0, 0, 0};
        if (hi) { p1.x = f2bf(acc1.x); p1.y = f2bf(acc1.y); p1.z = f2bf(acc1.z); p1.w = f2bf(acc1.w); }
        ob[lane + 64] = p1;   // lanes 61-63 zero-fill pad cols 500..511
    }
}

// ---------------- SpMM gather, D=10 ----------------
__global__ __launch_bounds__(256) void spmm_csr10(const int* __restrict__ rowptr,
                                                  const int* __restrict__ ecols,
                                                  const float* __restrict__ evals,
                                                  const float* __restrict__ S,
                                                  const float* __restrict__ T,
                                                  float* __restrict__ O,
                                                  int nrows, int domix) {
    int g = (int)((blockIdx.x * 256 + threadIdx.x) >> 4);
    int t = threadIdx.x & 15;
    if (g >= nrows || t >= 10) return;
    int beg = rowptr[g], end = rowptr[g + 1];
    float acc = 0.f;
    for (int e = beg; e < end; ++e)
        acc += evals[e] * S[(size_t)ecols[e] * 10 + t];
    if (domix) acc = 0.5f * fmaxf(acc, 0.f) + 0.5f * T[(size_t)g * 10 + t];
    O[(size_t)g * 10 + t] = acc;
}

extern "C" void kernel_launch(void* const* d_in, const int* in_sizes, int n_in,
                              void* d_out, int out_size, void* d_ws, size_t ws_size,
                              hipStream_t stream) {
    const float* x    = (const float*)d_in[0];
    const int*   ar   = (const int*)d_in[1];
    const int*   ac   = (const int*)d_in[2];
    const float* av   = (const float*)d_in[3];
    const float* tra1 = (const float*)d_in[4];
    const float* tra2 = (const float*)d_in[5];
    const float* tra3 = (const float*)d_in[6];
    const float* z    = (const float*)d_in[7];
    const float* W1   = (const float*)d_in[8];
    const float* W2   = (const float*)d_in[9];
    const float* W3   = (const float*)d_in[10];
    const float* W4   = (const float*)d_in[11];
    const float* W5   = (const float*)d_in[12];

    const int E = in_sizes[1];
    const int N = in_sizes[7] / 10;   // 50000
    const int NCH = (N + SCAN_CHUNK - 1) / SCAN_CHUNK;

    float*  A      = (float*)d_ws;                      // [N,500] f32 (m2 / small bufs)
    float*  Bb     = A + 25000000;                      // [N,500] f32 (supports)
    ushort* Abf    = (ushort*)(Bb + 25000000);          // [N,512] bf16
    ushort* Wt     = Abf + 25600000;                    // [2048,512] bf16 (transposed W)
    int*    ecols  = (int*)(Wt + 1048576);              // [E]
    float*  evals  = (float*)(ecols + E);               // [E]
    int*    rowptr = (int*)(evals + E);                 // [N+1]
    int*    cnt    = rowptr + (N + 1);                  // [N]
    int*    csum   = cnt + N;                           // [NCH]
    float*  Cc     = A + 1000000;                       // [CHUNK,2000] f32 (inside A, after col-10 region)
    float*  out    = (float*)d_out;

    dim3 blk(256);

    // ---- CSR build ----
    hipMemsetAsync(cnt, 0, (size_t)N * sizeof(int), stream);
    csr_count<<<(E + 255) / 256, blk, 0, stream>>>(ar, cnt, E);
    scan1<<<NCH, blk, 0, stream>>>(cnt, csum, N);
    scan2<<<1, 64, 0, stream>>>(csum, NCH);
    scan3<<<NCH, blk, 0, stream>>>(cnt, csum, rowptr, N, E);
    hipMemcpyAsync(cnt, rowptr, (size_t)N * sizeof(int), hipMemcpyDeviceToDevice, stream);
    csr_fill<<<(E + 255) / 256, blk, 0, stream>>>(ar, ac, av, cnt, ecols, evals, E);

    const int spmm500_blocks = (N * 64 + 255) / 256;
    const int spmm10_blocks  = (N * 16 + 255) / 256;

    // ---- Layer 1: Abf = bf16(x); support = Abf@W1t -> Bb; m1 = mix(spmm) -> Abf (bf16)
    cvt4<<<(int)(((long)N * 512 / 4 + 255) / 256), blk, 0, stream>>>(x, Abf, (long)N * 512 / 4);
    cvt_wt<<<(512 * 512 + 255) / 256, blk, 0, stream>>>(W1, Wt, 512, 500, 512);
    {
        dim3 g(4, (N + BM - 1) / BM);
        gemm_bf16<<<g, blk, 0, stream>>>(Abf, Wt, Bb, nullptr, N, 500, 0);
    }
    spmm_csr500<<<spmm500_blocks, blk, 0, stream>>>(rowptr, ecols, evals, Bb, tra1, nullptr, Abf, N, 2);

    // ---- Layer 2: support = Abf@W2t -> Bb; m2 = mix(spmm) -> A (f32)
    cvt_wt<<<(512 * 512 + 255) / 256, blk, 0, stream>>>(W2, Wt, 500, 500, 512);
    {
        dim3 g(4, (N + BM - 1) / BM);
        gemm_bf16<<<g, blk, 0, stream>>>(Abf, Wt, Bb, nullptr, N, 500, 0);
    }
    spmm_csr500<<<spmm500_blocks, blk, 0, stream>>>(rowptr, ecols, evals, Bb, tra2, A, nullptr, N, 1);

    // ---- Layer 3 (spmm-first): g = spmm(m2) -> Abf (bf16 raw)
    spmm_csr500<<<spmm500_blocks, blk, 0, stream>>>(rowptr, ecols, evals, A, nullptr, nullptr, Abf, N, 3);
    cvt_wt<<<(2048 * 512 + 255) / 256, blk, 0, stream>>>(W3, Wt, 500, 2000, 2048);

    for (int c = 0; c < N / CHUNK; ++c) {
        int r0 = c * CHUNK;
        dim3 g(16, (CHUNK + BM - 1) / BM);
        // Cc = 0.5*relu(g@W3) + 0.5*tra3  (epilogue-fused)
        gemm_bf16<<<g, blk, 0, stream>>>(Abf + (size_t)r0 * 512, Wt, Cc,
                                         tra3 + (size_t)r0 * 2000, CHUNK, 2000, 1);
        gemm_m10<<<(CHUNK * 64 + 255) / 256, blk, 0, stream>>>(Cc, W4, A + (size_t)r0 * 10, CHUNK, 2000);
    }

    // ---- Layer 4: m4 = mix(spmm(A[:,10]), z) -> Bb[:,10]
    spmm_csr10<<<spmm10_blocks, blk, 0, stream>>>(rowptr, ecols, evals, A, z, Bb, N, 1);

    // ---- Layer 5: support = m4@W5 -> A[:,10]; out = spmm (raw)
    gemm_m10<<<(N * 64 + 255) / 256, blk, 0, stream>>>(Bb, W5, A, N, 10);
    spmm_csr10<<<spmm10_blocks, blk, 0, stream>>>(rowptr, ecols, evals, A, nullptr, out, N, 0);
}

// Round 4
// 2081.225 us; speedup vs baseline: 17.6700x; 1.3580x over previous
//
#include <hip/hip_runtime.h>
#include <hip/hip_bf16.h>

// GNN: 5-layer GCN. Round 4: bf16 everywhere on the big streams.
// - GEMM (m97-style 128x128 MFMA tile) can emit f32 or bf16 (+fused relu/mix).
// - SpMM D=500 gathers bf16 [N,512] rows (16B/lane/edge), accumulates f32, emits bf16.
// - Layer 3: (SpMM(m2))@W3 associativity; W3 GEMM emits bf16 Cc; W4 reduce reads bf16.
// - CSR build (counting sort) per call; CSR gather has no atomics.

#define CHUNK 10000
#define SCAN_CHUNK 512
#define BM 128
#define BN 128
#define BK 64

typedef __attribute__((ext_vector_type(4))) float f32x4;
typedef __attribute__((ext_vector_type(8))) __bf16 bf16x8;
typedef __attribute__((ext_vector_type(8))) short s16x8;

__device__ __forceinline__ bf16x8 as_bf(s16x8 v) { union { s16x8 s; bf16x8 b; } u; u.s = v; return u.b; }
__device__ __forceinline__ ushort f2bf(float f) {
    uint u = __float_as_uint(f);
    return (ushort)((u + 0x7FFFu + ((u >> 16) & 1u)) >> 16);   // RNE
}
__device__ __forceinline__ float bf2f(ushort s) {
    return __uint_as_float(((uint)s) << 16);
}

#define GLL16(g, l)                                                                 \
    __builtin_amdgcn_global_load_lds((const __attribute__((address_space(1))) void*)(g), \
                                     (__attribute__((address_space(3))) void*)(l), 16, 0, 0)

// ---------------- bf16 MFMA GEMM: C = A[M,512]bf16 @ Bt[Npad,512]bf16^T ----------------
// mode: 0 = f32 raw, 1 = f32 mix, 2 = bf16 raw, 3 = bf16 mix. ldo = out stride
// (f32 modes: ldo == Nreal; bf16 modes: ldo = padded stride, pad cols written 0).
// mix: v = 0.5*relu(v) + 0.5*T[gr*Nreal+gc]
__global__ __launch_bounds__(256) void gemm_bf16(const ushort* __restrict__ A,
                                                 const ushort* __restrict__ Bt,
                                                 float* __restrict__ Cf,
                                                 ushort* __restrict__ Cb,
                                                 const float* __restrict__ T,
                                                 int M, int Nreal, int ldo, int mode) {
    __shared__ ushort As[BM * BK];   // [row][k] linear
    __shared__ ushort Bs[BN * BK];   // [col][k] linear
    int tid = threadIdx.x;
    int w = tid >> 6, l = tid & 63;
    int row0 = blockIdx.y * BM, col0 = blockIdx.x * BN;
    int wr = (w >> 1) * 64, wc = (w & 1) * 64;

    f32x4 acc[4][4] = {};

    int arow_off = w * 8 + (l >> 3);
    int acol = (l & 7) * 8;

    for (int k0 = 0; k0 < 512; k0 += BK) {
        __syncthreads();
#pragma unroll
        for (int i = 0; i < 4; ++i) {
            int ar = row0 + arow_off + i * 32;
            if (ar >= M) ar = M - 1;          // clamp; C write is guarded
            const ushort* ga = A + (size_t)ar * 512 + k0 + acol;
            GLL16(ga, &As[(w * 8 + i * 32) * BK]);
            const ushort* gb = Bt + (size_t)(col0 + arow_off + i * 32) * 512 + k0 + acol;
            GLL16(gb, &Bs[(w * 8 + i * 32) * BK]);
        }
        __syncthreads();
#pragma unroll
        for (int s = 0; s < 2; ++s) {
            int kb = s * 32 + (l >> 4) * 8;
            bf16x8 af[4], bfr[4];
#pragma unroll
            for (int m = 0; m < 4; ++m)
                af[m] = as_bf(*(const s16x8*)&As[(wr + m * 16 + (l & 15)) * BK + kb]);
#pragma unroll
            for (int n = 0; n < 4; ++n)
                bfr[n] = as_bf(*(const s16x8*)&Bs[(wc + n * 16 + (l & 15)) * BK + kb]);
#pragma unroll
            for (int m = 0; m < 4; ++m)
#pragma unroll
                for (int n = 0; n < 4; ++n)
                    acc[m][n] = __builtin_amdgcn_mfma_f32_16x16x32_bf16(af[m], bfr[n], acc[m][n], 0, 0, 0);
        }
    }
    int crow = (l >> 4) * 4;
    int ccol = l & 15;
#pragma unroll
    for (int m = 0; m < 4; ++m)
#pragma unroll
        for (int n = 0; n < 4; ++n) {
            int gc = col0 + wc + n * 16 + ccol;
#pragma unroll
            for (int r = 0; r < 4; ++r) {
                int gr = row0 + wr + m * 16 + crow + r;
                if (gr >= M) continue;
                float v = acc[m][n][r];
                if (mode <= 1) {
                    if (gc >= Nreal) continue;
                    size_t idx = (size_t)gr * Nreal + gc;
                    if (mode == 1) v = 0.5f * fmaxf(v, 0.f) + 0.5f * T[idx];
                    Cf[idx] = v;
                } else {
                    if (gc >= ldo) continue;
                    float o = 0.f;
                    if (gc < Nreal) {
                        o = v;
                        if (mode == 3) o = 0.5f * fmaxf(o, 0.f) + 0.5f * T[(size_t)gr * Nreal + gc];
                    }
                    Cb[(size_t)gr * ldo + gc] = f2bf(o);
                }
            }
        }
}

// ---------------- wave-per-row GEMM, 10 outputs, f32 A ----------------
__global__ __launch_bounds__(256) void gemm_m10(const float* __restrict__ A,
                                                const float* __restrict__ B,
                                                float* __restrict__ C,
                                                int rows, int K) {
    int wave = (int)((blockIdx.x * 256 + threadIdx.x) >> 6);
    int lane = threadIdx.x & 63;
    if (wave >= rows) return;
    const float* a = A + (size_t)wave * K;
    float acc[10];
#pragma unroll
    for (int j = 0; j < 10; ++j) acc[j] = 0.f;
    for (int k = lane; k < K; k += 64) {
        float av = a[k];
        const float* b = B + (size_t)k * 10;
#pragma unroll
        for (int j = 0; j < 10; ++j) acc[j] += av * b[j];
    }
#pragma unroll
    for (int off = 32; off; off >>= 1) {
#pragma unroll
        for (int j = 0; j < 10; ++j) acc[j] += __shfl_down(acc[j], off, 64);
    }
    if (lane == 0) {
        float* c = C + (size_t)wave * 10;
#pragma unroll
        for (int j = 0; j < 10; ++j) c[j] = acc[j];
    }
}

// ---------------- wave-per-row GEMM, 10 outputs, bf16 A (stride lda, K real) ----------
__global__ __launch_bounds__(256) void gemm_m10_bf(const ushort* __restrict__ A,
                                                   const float* __restrict__ B,
                                                   float* __restrict__ C,
                                                   int rows, int K, int lda) {
    int wave = (int)((blockIdx.x * 256 + threadIdx.x) >> 6);
    int lane = threadIdx.x & 63;
    if (wave >= rows) return;
    const ushort* a = A + (size_t)wave * lda;
    float acc[10];
#pragma unroll
    for (int j = 0; j < 10; ++j) acc[j] = 0.f;
    int quads = K >> 2;
    for (int q = lane; q < quads; q += 64) {
        ushort4 av = ((const ushort4*)a)[q];
        float a0 = bf2f(av.x), a1 = bf2f(av.y), a2 = bf2f(av.z), a3 = bf2f(av.w);
        const float* b0 = B + (size_t)(q * 4) * 10;
#pragma unroll
        for (int j = 0; j < 10; ++j)
            acc[j] += a0 * b0[j] + a1 * b0[10 + j] + a2 * b0[20 + j] + a3 * b0[30 + j];
    }
#pragma unroll
    for (int off = 32; off; off >>= 1) {
#pragma unroll
        for (int j = 0; j < 10; ++j) acc[j] += __shfl_down(acc[j], off, 64);
    }
    if (lane == 0) {
        float* c = C + (size_t)wave * 10;
#pragma unroll
        for (int j = 0; j < 10; ++j) c[j] = acc[j];
    }
}

// ---------------- conversions ----------------
__global__ __launch_bounds__(256) void cvt4(const float* __restrict__ s,
                                            ushort* __restrict__ d, long n4) {
    long i = (long)blockIdx.x * 256 + threadIdx.x;
    if (i >= n4) return;
    float4 v = ((const float4*)s)[i];
    ushort4 o = { f2bf(v.x), f2bf(v.y), f2bf(v.z), f2bf(v.w) };
    ((ushort4*)d)[i] = o;
}

// Wt[n][k] (Npad x 512) = bf16(W[k][n]), zero-padded
__global__ __launch_bounds__(256) void cvt_wt(const float* __restrict__ W,
                                              ushort* __restrict__ Wt,
                                              int Ksrc, int Nsrc, int Npad) {
    int i = blockIdx.x * 256 + threadIdx.x;
    if (i >= Npad * 512) return;
    int n = i >> 9, k = i & 511;
    float v = (k < Ksrc && n < Nsrc) ? W[(size_t)k * Nsrc + n] : 0.f;
    Wt[i] = f2bf(v);
}

// ---------------- CSR build: count / scan / fill ----------------
__global__ __launch_bounds__(256) void csr_count(const int* __restrict__ rows,
                                                 int* __restrict__ cnt, int E) {
    int e = blockIdx.x * 256 + threadIdx.x;
    if (e < E) atomicAdd(&cnt[rows[e]], 1);
}

__global__ __launch_bounds__(256) void scan1(const int* __restrict__ cnt,
                                             int* __restrict__ csum, int n) {
    __shared__ int red[256];
    int base = blockIdx.x * SCAN_CHUNK;
    int t = threadIdx.x;
    int s = 0;
    if (base + t < n) s += cnt[base + t];
    if (base + t + 256 < n) s += cnt[base + t + 256];
    red[t] = s;
    __syncthreads();
    for (int off = 128; off; off >>= 1) {
        if (t < off) red[t] += red[t + off];
        __syncthreads();
    }
    if (t == 0) csum[blockIdx.x] = red[0];
}

__global__ void scan2(int* csum, int nch) {
    if (threadIdx.x == 0 && blockIdx.x == 0) {
        int acc = 0;
        for (int i = 0; i < nch; ++i) { int v = csum[i]; csum[i] = acc; acc += v; }
    }
}

__global__ __launch_bounds__(256) void scan3(const int* __restrict__ cnt,
                                             const int* __restrict__ csum,
                                             int* __restrict__ rowptr, int n, int E) {
    __shared__ int sm[SCAN_CHUNK];
    int base = blockIdx.x * SCAN_CHUNK;
    int t = threadIdx.x;
    for (int i = t; i < SCAN_CHUNK; i += 256) sm[i] = (base + i < n) ? cnt[base + i] : 0;
    __syncthreads();
    for (int off = 1; off < SCAN_CHUNK; off <<= 1) {
        int i0 = t, i1 = t + 256;
        int v0 = (i0 >= off) ? sm[i0 - off] : 0;
        int v1 = (i1 >= off) ? sm[i1 - off] : 0;
        __syncthreads();
        sm[i0] += v0;
        sm[i1] += v1;
        __syncthreads();
    }
    int off0 = csum[blockIdx.x];
    for (int i = t; i < SCAN_CHUNK; i += 256)
        if (base + i < n) rowptr[base + i] = off0 + (i ? sm[i - 1] : 0);
    if (blockIdx.x == 0 && t == 0) rowptr[n] = E;
}

__global__ __launch_bounds__(256) void csr_fill(const int* __restrict__ rows,
                                                const int* __restrict__ cols,
                                                const float* __restrict__ vals,
                                                int* __restrict__ cur,
                                                int* __restrict__ ecols,
                                                float* __restrict__ evals, int E) {
    int e = blockIdx.x * 256 + threadIdx.x;
    if (e >= E) return;
    int p = atomicAdd(&cur[rows[e]], 1);
    ecols[p] = cols[e];
    evals[p] = vals[e];
}

// ---------------- SpMM gather, bf16 source [nrows,512]: wave per row ----------------
// One s16x8 (16B) load per lane per edge. f32 accumulate. Output bf16 [nrows,512],
// pad cols 500..511 written 0. domix: res = 0.5*relu(acc)+0.5*T[row*500+c].
__global__ __launch_bounds__(256) void spmm_bf(const int* __restrict__ rowptr,
                                               const int* __restrict__ ecols,
                                               const float* __restrict__ evals,
                                               const ushort* __restrict__ S,
                                               const float* __restrict__ T,
                                               ushort* __restrict__ O,
                                               int nrows, int domix) {
    int wid = (int)((blockIdx.x * 256 + threadIdx.x) >> 6);
    int lane = threadIdx.x & 63;
    if (wid >= nrows) return;
    int beg = rowptr[wid], end = rowptr[wid + 1];
    float acc[8] = {0.f, 0.f, 0.f, 0.f, 0.f, 0.f, 0.f, 0.f};
    int e = beg;
    for (; e + 1 < end; e += 2) {
        int ca = ecols[e], cb = ecols[e + 1];
        float va = evals[e], vb = evals[e + 1];
        s16x8 a = ((const s16x8*)(S + (size_t)ca * 512))[lane];
        s16x8 b = ((const s16x8*)(S + (size_t)cb * 512))[lane];
#pragma unroll
        for (int j = 0; j < 8; ++j)
            acc[j] += va * bf2f((ushort)a[j]) + vb * bf2f((ushort)b[j]);
    }
    if (e < end) {
        int ca = ecols[e];
        float va = evals[e];
        s16x8 a = ((const s16x8*)(S + (size_t)ca * 512))[lane];
#pragma unroll
        for (int j = 0; j < 8; ++j)
            acc[j] += va * bf2f((ushort)a[j]);
    }
    int c0 = lane * 8;
    float res[8];
    if (domix) {
        float tv[8] = {0.f, 0.f, 0.f, 0.f, 0.f, 0.f, 0.f, 0.f};
        const float* trow = T + (size_t)wid * 500;
        if (c0 + 8 <= 500) {
            float4 t0 = *(const float4*)(trow + c0);
            float4 t1 = *(const float4*)(trow + c0 + 4);
            tv[0] = t0.x; tv[1] = t0.y; tv[2] = t0.z; tv[3] = t0.w;
            tv[4] = t1.x; tv[5] = t1.y; tv[6] = t1.z; tv[7] = t1.w;
        } else {
#pragma unroll
            for (int j = 0; j < 8; ++j)
                if (c0 + j < 500) tv[j] = trow[c0 + j];
        }
#pragma unroll
        for (int j = 0; j < 8; ++j)
            res[j] = (c0 + j < 500) ? (0.5f * fmaxf(acc[j], 0.f) + 0.5f * tv[j]) : 0.f;
    } else {
#pragma unroll
        for (int j = 0; j < 8; ++j)
            res[j] = (c0 + j < 500) ? acc[j] : 0.f;
    }
    s16x8 o;
#pragma unroll
    for (int j = 0; j < 8; ++j) o[j] = (short)f2bf(res[j]);
    ((s16x8*)(O + (size_t)wid * 512))[lane] = o;
}

// ---------------- SpMM gather, D=10, f32 ----------------
__global__ __launch_bounds__(256) void spmm_csr10(const int* __restrict__ rowptr,
                                                  const int* __restrict__ ecols,
                                                  const float* __restrict__ evals,
                                                  const float* __restrict__ S,
                                                  const float* __restrict__ T,
                                                  float* __restrict__ O,
                                                  int nrows, int domix) {
    int g = (int)((blockIdx.x * 256 + threadIdx.x) >> 4);
    int t = threadIdx.x & 15;
    if (g >= nrows || t >= 10) return;
    int beg = rowptr[g], end = rowptr[g + 1];
    float acc = 0.f;
    for (int e = beg; e < end; ++e)
        acc += evals[e] * S[(size_t)ecols[e] * 10 + t];
    if (domix) acc = 0.5f * fmaxf(acc, 0.f) + 0.5f * T[(size_t)g * 10 + t];
    O[(size_t)g * 10 + t] = acc;
}

extern "C" void kernel_launch(void* const* d_in, const int* in_sizes, int n_in,
                              void* d_out, int out_size, void* d_ws, size_t ws_size,
                              hipStream_t stream) {
    const float* x    = (const float*)d_in[0];
    const int*   ar   = (const int*)d_in[1];
    const int*   ac   = (const int*)d_in[2];
    const float* av   = (const float*)d_in[3];
    const float* tra1 = (const float*)d_in[4];
    const float* tra2 = (const float*)d_in[5];
    const float* tra3 = (const float*)d_in[6];
    const float* z    = (const float*)d_in[7];
    const float* W1   = (const float*)d_in[8];
    const float* W2   = (const float*)d_in[9];
    const float* W3   = (const float*)d_in[10];
    const float* W4   = (const float*)d_in[11];
    const float* W5   = (const float*)d_in[12];

    const int E = in_sizes[1];
    const int N = in_sizes[7] / 10;   // 50000
    const int NCH = (N + SCAN_CHUNK - 1) / SCAN_CHUNK;

    // workspace layout (~259 MB)
    float*  Af     = (float*)d_ws;                       // 25M floats: [0,500K) support4;
                                                         // [500K,1M) m4; [1M,1.5M) support5
    ushort* Abf    = (ushort*)(Af + 25000000);           // [N,512] bf16 (h / mix buffers)
    ushort* Sbf    = Abf + 25600000;                     // [N,512] bf16 (supports / g)
    ushort* Cbf    = Sbf + 25600000;                     // [CHUNK,2048] bf16 (layer-3 act)
    ushort* Wt     = Cbf + (size_t)CHUNK * 2048;         // [2048,512] bf16
    int*    ecols  = (int*)(Wt + 1048576);               // [E]
    float*  evals  = (float*)(ecols + E);                // [E]
    int*    rowptr = (int*)(evals + E);                  // [N+1]
    int*    cnt    = rowptr + (N + 1);                   // [N]
    int*    csum   = cnt + N;                            // [NCH]
    float*  sup4   = Af;
    float*  m4     = Af + 500000;
    float*  sup5   = Af + 1000000;
    float*  out    = (float*)d_out;

    dim3 blk(256);

    // ---- CSR build ----
    hipMemsetAsync(cnt, 0, (size_t)N * sizeof(int), stream);
    csr_count<<<(E + 255) / 256, blk, 0, stream>>>(ar, cnt, E);
    scan1<<<NCH, blk, 0, stream>>>(cnt, csum, N);
    scan2<<<1, 64, 0, stream>>>(csum, NCH);
    scan3<<<NCH, blk, 0, stream>>>(cnt, csum, rowptr, N, E);
    hipMemcpyAsync(cnt, rowptr, (size_t)N * sizeof(int), hipMemcpyDeviceToDevice, stream);
    csr_fill<<<(E + 255) / 256, blk, 0, stream>>>(ar, ac, av, cnt, ecols, evals, E);

    const int spmm_blocks   = (N * 64 + 255) / 256;
    const int spmm10_blocks = (N * 16 + 255) / 256;

    // ---- Layer 1: Abf = bf16(x); Sbf = Abf@W1t (bf16 raw); Abf = mix(spmm, tra1)
    cvt4<<<(int)(((long)N * 512 / 4 + 255) / 256), blk, 0, stream>>>(x, Abf, (long)N * 512 / 4);
    cvt_wt<<<(512 * 512 + 255) / 256, blk, 0, stream>>>(W1, Wt, 512, 500, 512);
    {
        dim3 g(4, (N + BM - 1) / BM);
        gemm_bf16<<<g, blk, 0, stream>>>(Abf, Wt, nullptr, Sbf, nullptr, N, 500, 512, 2);
    }
    spmm_bf<<<spmm_blocks, blk, 0, stream>>>(rowptr, ecols, evals, Sbf, tra1, Abf, N, 1);

    // ---- Layer 2: Sbf = Abf@W2t; Abf(m2) = mix(spmm, tra2)
    cvt_wt<<<(512 * 512 + 255) / 256, blk, 0, stream>>>(W2, Wt, 500, 500, 512);
    {
        dim3 g(4, (N + BM - 1) / BM);
        gemm_bf16<<<g, blk, 0, stream>>>(Abf, Wt, nullptr, Sbf, nullptr, N, 500, 512, 2);
    }
    spmm_bf<<<spmm_blocks, blk, 0, stream>>>(rowptr, ecols, evals, Sbf, tra2, Abf, N, 1);

    // ---- Layer 3 (spmm-first): Sbf(g) = spmm(m2) raw; chunked: Cbf = mix(g@W3, tra3); sup4 = Cbf@W4
    spmm_bf<<<spmm_blocks, blk, 0, stream>>>(rowptr, ecols, evals, Abf, nullptr, Sbf, N, 0);
    cvt_wt<<<(2048 * 512 + 255) / 256, blk, 0, stream>>>(W3, Wt, 500, 2000, 2048);

    for (int c = 0; c < N / CHUNK; ++c) {
        int r0 = c * CHUNK;
        dim3 g(16, (CHUNK + BM - 1) / BM);
        gemm_bf16<<<g, blk, 0, stream>>>(Sbf + (size_t)r0 * 512, Wt, nullptr, Cbf,
                                         tra3 + (size_t)r0 * 2000, CHUNK, 2000, 2048, 3);
        gemm_m10_bf<<<(CHUNK * 64 + 255) / 256, blk, 0, stream>>>(Cbf, W4, sup4 + (size_t)r0 * 10,
                                                                  CHUNK, 2000, 2048);
    }

    // ---- Layer 4: m4 = mix(spmm(sup4), z)
    spmm_csr10<<<spmm10_blocks, blk, 0, stream>>>(rowptr, ecols, evals, sup4, z, m4, N, 1);

    // ---- Layer 5: sup5 = m4@W5; out = spmm(sup5) raw
    gemm_m10<<<(N * 64 + 255) / 256, blk, 0, stream>>>(m4, W5, sup5, N, 10);
    spmm_csr10<<<spmm10_blocks, blk, 0, stream>>>(rowptr, ecols, evals, sup5, nullptr, out, N, 0);
}

// Round 5
// 1669.614 us; speedup vs baseline: 22.0261x; 1.2465x over previous
//
#include <hip/hip_runtime.h>
#include <hip/hip_bf16.h>

// GNN: 5-layer GCN on MI355X. Round 5:
// - Layer 3 fully fused: gemm3_w4 computes act = mix(relu(g@W3), tra3) in registers,
//   spills the 128x128 act tile to LDS (bf16, stride 136), second-stage MFMA with
//   W4 (bf16, staged in disjoint LDS region), atomicAdd f32 partials into sup4.
//   Eliminates the [N,2048] activation buffer (400 MB round trip) and chunking.
// - Edges packed int2 (col, val-bits): one 8B load per edge.
// - m4@W5 fused into spmm10 epilogue via __shfl within 16-thread group.
// - SpMM D=500: CSR gather, bf16 [N,512] source, wave/row, f32 accum, bf16 out.

#define SCAN_CHUNK 512
#define BM 128
#define BN 128
#define BK 64

typedef __attribute__((ext_vector_type(4))) float f32x4;
typedef __attribute__((ext_vector_type(8))) __bf16 bf16x8;
typedef __attribute__((ext_vector_type(8))) short s16x8;

__device__ __forceinline__ bf16x8 as_bf(s16x8 v) { union { s16x8 s; bf16x8 b; } u; u.s = v; return u.b; }
__device__ __forceinline__ ushort f2bf(float f) {
    uint u = __float_as_uint(f);
    return (ushort)((u + 0x7FFFu + ((u >> 16) & 1u)) >> 16);   // RNE
}
__device__ __forceinline__ float bf2f(ushort s) { return __uint_as_float(((uint)s) << 16); }

#define GLL16(g, l)                                                                 \
    __builtin_amdgcn_global_load_lds((const __attribute__((address_space(1))) void*)(g), \
                                     (__attribute__((address_space(3))) void*)(l), 16, 0, 0)

// ---------------- support GEMM: C[M,512]bf16 = A[M,512]bf16 @ Bt[512,512]bf16^T ------
// Bt pad rows are zero, so pad output cols come out 0 naturally.
__global__ __launch_bounds__(256) void gemm_sup(const ushort* __restrict__ A,
                                                const ushort* __restrict__ Bt,
                                                ushort* __restrict__ C, int M) {
    __shared__ ushort As[BM * BK];
    __shared__ ushort Bs[BN * BK];
    int tid = threadIdx.x;
    int w = tid >> 6, l = tid & 63;
    int row0 = blockIdx.y * BM, col0 = blockIdx.x * BN;
    int wr = (w >> 1) * 64, wc = (w & 1) * 64;
    f32x4 acc[4][4] = {};
    int arow_off = w * 8 + (l >> 3);
    int acol = (l & 7) * 8;
    for (int k0 = 0; k0 < 512; k0 += BK) {
        __syncthreads();
#pragma unroll
        for (int i = 0; i < 4; ++i) {
            int ar = row0 + arow_off + i * 32;
            if (ar >= M) ar = M - 1;
            GLL16(A + (size_t)ar * 512 + k0 + acol, &As[(w * 8 + i * 32) * BK]);
            GLL16(Bt + (size_t)(col0 + arow_off + i * 32) * 512 + k0 + acol, &Bs[(w * 8 + i * 32) * BK]);
        }
        __syncthreads();
#pragma unroll
        for (int s = 0; s < 2; ++s) {
            int kb = s * 32 + (l >> 4) * 8;
            bf16x8 af[4], bfr[4];
#pragma unroll
            for (int m = 0; m < 4; ++m)
                af[m] = as_bf(*(const s16x8*)&As[(wr + m * 16 + (l & 15)) * BK + kb]);
#pragma unroll
            for (int n = 0; n < 4; ++n)
                bfr[n] = as_bf(*(const s16x8*)&Bs[(wc + n * 16 + (l & 15)) * BK + kb]);
#pragma unroll
            for (int m = 0; m < 4; ++m)
#pragma unroll
                for (int n = 0; n < 4; ++n)
                    acc[m][n] = __builtin_amdgcn_mfma_f32_16x16x32_bf16(af[m], bfr[n], acc[m][n], 0, 0, 0);
        }
    }
    int crow = (l >> 4) * 4, ccol = l & 15;
#pragma unroll
    for (int m = 0; m < 4; ++m)
#pragma unroll
        for (int n = 0; n < 4; ++n) {
            int gc = col0 + wc + n * 16 + ccol;
#pragma unroll
            for (int r = 0; r < 4; ++r) {
                int gr = row0 + wr + m * 16 + crow + r;
                if (gr < M) C[(size_t)gr * 512 + gc] = f2bf(acc[m][n][r]);
            }
        }
}

// ---------------- fused layer-3: sup4 += (mix(relu(g@W3), tra3)) @ W4 ----------------
// A: g [M,512] bf16. Bt: Wt3 [2048,512] bf16 (pad rows zero). T: tra3 [M,2000] f32.
// W4: [2000,10] f32. sup4: [M,10] f32 (pre-zeroed; 16 col-blocks atomicAdd partials).
#define ASTR 136   // act LDS stride (ushorts): 272B rows -> b128-aligned, banks spread
__global__ __launch_bounds__(256) void gemm3_w4(const ushort* __restrict__ A,
                                                const ushort* __restrict__ Bt,
                                                const float* __restrict__ T,
                                                const float* __restrict__ W4,
                                                float* __restrict__ sup4, int M) {
    __shared__ ushort lds[19584];          // 39.2 KB
    ushort* As   = lds;                    // [128*64] main loop
    ushort* Bs   = lds + 8192;             // [128*64]
    ushort* actS = lds;                    // [128][136] epilogue (overlays As/Bs)
    ushort* W4S  = lds + 17408;            // [16][136]  (disjoint from As/Bs)
    int tid = threadIdx.x;
    int w = tid >> 6, l = tid & 63;
    int row0 = blockIdx.y * BM, col0 = blockIdx.x * BN;
    int wr = (w >> 1) * 64, wc = (w & 1) * 64;

    // stage W4 fragment region (B-frag layout: [col j][k local]); untouched by main loop
    {
        int j = tid & 15, k0l = (tid >> 4) * 8;
#pragma unroll
        for (int kk = 0; kk < 8; ++kk) {
            int gk = col0 + k0l + kk;
            float v = (j < 10 && gk < 2000) ? W4[(size_t)gk * 10 + j] : 0.f;
            W4S[j * ASTR + k0l + kk] = f2bf(v);
        }
    }

    f32x4 acc[4][4] = {};
    int arow_off = w * 8 + (l >> 3);
    int acol = (l & 7) * 8;
    for (int k0 = 0; k0 < 512; k0 += BK) {
        __syncthreads();
#pragma unroll
        for (int i = 0; i < 4; ++i) {
            int ar = row0 + arow_off + i * 32;
            if (ar >= M) ar = M - 1;
            GLL16(A + (size_t)ar * 512 + k0 + acol, &As[(w * 8 + i * 32) * BK]);
            GLL16(Bt + (size_t)(col0 + arow_off + i * 32) * 512 + k0 + acol, &Bs[(w * 8 + i * 32) * BK]);
        }
        __syncthreads();
#pragma unroll
        for (int s = 0; s < 2; ++s) {
            int kb = s * 32 + (l >> 4) * 8;
            bf16x8 af[4], bfr[4];
#pragma unroll
            for (int m = 0; m < 4; ++m)
                af[m] = as_bf(*(const s16x8*)&As[(wr + m * 16 + (l & 15)) * BK + kb]);
#pragma unroll
            for (int n = 0; n < 4; ++n)
                bfr[n] = as_bf(*(const s16x8*)&Bs[(wc + n * 16 + (l & 15)) * BK + kb]);
#pragma unroll
            for (int m = 0; m < 4; ++m)
#pragma unroll
                for (int n = 0; n < 4; ++n)
                    acc[m][n] = __builtin_amdgcn_mfma_f32_16x16x32_bf16(af[m], bfr[n], acc[m][n], 0, 0, 0);
        }
    }

    // epilogue: act tile (mix applied) -> LDS bf16
    __syncthreads();
    int crow = (l >> 4) * 4, ccol = l & 15;
#pragma unroll
    for (int m = 0; m < 4; ++m)
#pragma unroll
        for (int n = 0; n < 4; ++n) {
            int cl = wc + n * 16 + ccol;
            int gc = col0 + cl;
#pragma unroll
            for (int r = 0; r < 4; ++r) {
                int rl = wr + m * 16 + crow + r;
                int gr = row0 + rl;
                float v = 0.f;
                if (gr < M && gc < 2000)
                    v = 0.5f * fmaxf(acc[m][n][r], 0.f) + 0.5f * T[(size_t)gr * 2000 + gc];
                actS[rl * ASTR + cl] = f2bf(v);
            }
        }
    __syncthreads();

    // stage 2: [128 rows][128 k] @ [16 cols][128 k]; each wave: its 64 rows x its 64-k half
    f32x4 acc2[4] = {};
#pragma unroll
    for (int s = 0; s < 2; ++s) {
        int kb = wc + s * 32 + (l >> 4) * 8;
        bf16x8 bfw = as_bf(*(const s16x8*)&W4S[ccol * ASTR + kb]);
#pragma unroll
        for (int m = 0; m < 4; ++m) {
            bf16x8 af = as_bf(*(const s16x8*)&actS[(wr + m * 16 + ccol) * ASTR + kb]);
            acc2[m] = __builtin_amdgcn_mfma_f32_16x16x32_bf16(af, bfw, acc2[m], 0, 0, 0);
        }
    }
    if (ccol < 10) {
#pragma unroll
        for (int m = 0; m < 4; ++m)
#pragma unroll
            for (int r = 0; r < 4; ++r) {
                int gr = row0 + wr + m * 16 + crow + r;
                if (gr < M) atomicAdd(&sup4[(size_t)gr * 10 + ccol], acc2[m][r]);
            }
    }
}

// ---------------- conversions ----------------
__global__ __launch_bounds__(256) void cvt4(const float* __restrict__ s,
                                            ushort* __restrict__ d, long n4) {
    long i = (long)blockIdx.x * 256 + threadIdx.x;
    if (i >= n4) return;
    float4 v = ((const float4*)s)[i];
    ushort4 o = { f2bf(v.x), f2bf(v.y), f2bf(v.z), f2bf(v.w) };
    ((ushort4*)d)[i] = o;
}

// Wt[n][k] (Npad x 512) = bf16(W[k][n]), zero-padded
__global__ __launch_bounds__(256) void cvt_wt(const float* __restrict__ W,
                                              ushort* __restrict__ Wt,
                                              int Ksrc, int Nsrc, int Npad) {
    int i = blockIdx.x * 256 + threadIdx.x;
    if (i >= Npad * 512) return;
    int n = i >> 9, k = i & 511;
    float v = (k < Ksrc && n < Nsrc) ? W[(size_t)k * Nsrc + n] : 0.f;
    Wt[i] = f2bf(v);
}

// ---------------- CSR build: count / scan / fill ----------------
__global__ __launch_bounds__(256) void csr_count(const int* __restrict__ rows,
                                                 int* __restrict__ cnt, int E) {
    int e = blockIdx.x * 256 + threadIdx.x;
    if (e < E) atomicAdd(&cnt[rows[e]], 1);
}

__global__ __launch_bounds__(256) void scan1(const int* __restrict__ cnt,
                                             int* __restrict__ csum, int n) {
    __shared__ int red[256];
    int base = blockIdx.x * SCAN_CHUNK;
    int t = threadIdx.x;
    int s = 0;
    if (base + t < n) s += cnt[base + t];
    if (base + t + 256 < n) s += cnt[base + t + 256];
    red[t] = s;
    __syncthreads();
    for (int off = 128; off; off >>= 1) {
        if (t < off) red[t] += red[t + off];
        __syncthreads();
    }
    if (t == 0) csum[blockIdx.x] = red[0];
}

__global__ void scan2(int* csum, int nch) {
    if (threadIdx.x == 0 && blockIdx.x == 0) {
        int acc = 0;
        for (int i = 0; i < nch; ++i) { int v = csum[i]; csum[i] = acc; acc += v; }
    }
}

__global__ __launch_bounds__(256) void scan3(const int* __restrict__ cnt,
                                             const int* __restrict__ csum,
                                             int* __restrict__ rowptr, int n, int E) {
    __shared__ int sm[SCAN_CHUNK];
    int base = blockIdx.x * SCAN_CHUNK;
    int t = threadIdx.x;
    for (int i = t; i < SCAN_CHUNK; i += 256) sm[i] = (base + i < n) ? cnt[base + i] : 0;
    __syncthreads();
    for (int off = 1; off < SCAN_CHUNK; off <<= 1) {
        int i0 = t, i1 = t + 256;
        int v0 = (i0 >= off) ? sm[i0 - off] : 0;
        int v1 = (i1 >= off) ? sm[i1 - off] : 0;
        __syncthreads();
        sm[i0] += v0;
        sm[i1] += v1;
        __syncthreads();
    }
    int off0 = csum[blockIdx.x];
    for (int i = t; i < SCAN_CHUNK; i += 256)
        if (base + i < n) rowptr[base + i] = off0 + (i ? sm[i - 1] : 0);
    if (blockIdx.x == 0 && t == 0) rowptr[n] = E;
}

__global__ __launch_bounds__(256) void csr_fill(const int* __restrict__ rows,
                                                const int* __restrict__ cols,
                                                const float* __restrict__ vals,
                                                int* __restrict__ cur,
                                                int2* __restrict__ edges, int E) {
    int e = blockIdx.x * 256 + threadIdx.x;
    if (e >= E) return;
    int p = atomicAdd(&cur[rows[e]], 1);
    edges[p] = make_int2(cols[e], __float_as_int(vals[e]));
}

// ---------------- SpMM gather, bf16 source [nrows,512]: wave per row ----------------
__global__ __launch_bounds__(256) void spmm_bf(const int* __restrict__ rowptr,
                                               const int2* __restrict__ edges,
                                               const ushort* __restrict__ S,
                                               const float* __restrict__ T,
                                               ushort* __restrict__ O,
                                               int nrows, int domix) {
    int wid = (int)((blockIdx.x * 256 + threadIdx.x) >> 6);
    int lane = threadIdx.x & 63;
    if (wid >= nrows) return;
    int beg = rowptr[wid], end = rowptr[wid + 1];
    float acc[8] = {0.f, 0.f, 0.f, 0.f, 0.f, 0.f, 0.f, 0.f};
    int e = beg;
    for (; e + 1 < end; e += 2) {
        int2 e0 = edges[e], e1 = edges[e + 1];
        float va = __int_as_float(e0.y), vb = __int_as_float(e1.y);
        s16x8 a = ((const s16x8*)(S + (size_t)e0.x * 512))[lane];
        s16x8 b = ((const s16x8*)(S + (size_t)e1.x * 512))[lane];
#pragma unroll
        for (int j = 0; j < 8; ++j)
            acc[j] += va * bf2f((ushort)a[j]) + vb * bf2f((ushort)b[j]);
    }
    if (e < end) {
        int2 e0 = edges[e];
        float va = __int_as_float(e0.y);
        s16x8 a = ((const s16x8*)(S + (size_t)e0.x * 512))[lane];
#pragma unroll
        for (int j = 0; j < 8; ++j)
            acc[j] += va * bf2f((ushort)a[j]);
    }
    int c0 = lane * 8;
    float res[8];
    if (domix) {
        float tv[8] = {0.f, 0.f, 0.f, 0.f, 0.f, 0.f, 0.f, 0.f};
        const float* trow = T + (size_t)wid * 500;
        if (c0 + 8 <= 500) {
            float4 t0 = *(const float4*)(trow + c0);
            float4 t1 = *(const float4*)(trow + c0 + 4);
            tv[0] = t0.x; tv[1] = t0.y; tv[2] = t0.z; tv[3] = t0.w;
            tv[4] = t1.x; tv[5] = t1.y; tv[6] = t1.z; tv[7] = t1.w;
        } else {
#pragma unroll
            for (int j = 0; j < 8; ++j)
                if (c0 + j < 500) tv[j] = trow[c0 + j];
        }
#pragma unroll
        for (int j = 0; j < 8; ++j)
            res[j] = (c0 + j < 500) ? (0.5f * fmaxf(acc[j], 0.f) + 0.5f * tv[j]) : 0.f;
    } else {
#pragma unroll
        for (int j = 0; j < 8; ++j)
            res[j] = (c0 + j < 500) ? acc[j] : 0.f;
    }
    s16x8 o;
#pragma unroll
    for (int j = 0; j < 8; ++j) o[j] = (short)f2bf(res[j]);
    ((s16x8*)(O + (size_t)wid * 512))[lane] = o;
}

// ---------------- SpMM gather, D=10 f32; optional fused mix+@W5 epilogue -------------
__global__ __launch_bounds__(256) void spmm10(const int* __restrict__ rowptr,
                                              const int2* __restrict__ edges,
                                              const float* __restrict__ S,
                                              const float* __restrict__ T,
                                              const float* __restrict__ W5,
                                              float* __restrict__ O, int nrows) {
    int g = (int)((blockIdx.x * 256 + threadIdx.x) >> 4);
    int t = threadIdx.x & 15;
    if (g >= nrows || t >= 10) return;
    int beg = rowptr[g], end = rowptr[g + 1];
    float acc = 0.f;
    for (int e = beg; e < end; ++e) {
        int2 ed = edges[e];
        acc += __int_as_float(ed.y) * S[(size_t)ed.x * 10 + t];
    }
    if (W5) {
        float m = 0.5f * fmaxf(acc, 0.f) + 0.5f * T[(size_t)g * 10 + t];
        float s5 = 0.f;
#pragma unroll
        for (int i = 0; i < 10; ++i)
            s5 += __shfl(m, i, 16) * W5[i * 10 + t];
        O[(size_t)g * 10 + t] = s5;
    } else {
        O[(size_t)g * 10 + t] = acc;
    }
}

extern "C" void kernel_launch(void* const* d_in, const int* in_sizes, int n_in,
                              void* d_out, int out_size, void* d_ws, size_t ws_size,
                              hipStream_t stream) {
    const float* x    = (const float*)d_in[0];
    const int*   ar   = (const int*)d_in[1];
    const int*   ac   = (const int*)d_in[2];
    const float* av   = (const float*)d_in[3];
    const float* tra1 = (const float*)d_in[4];
    const float* tra2 = (const float*)d_in[5];
    const float* tra3 = (const float*)d_in[6];
    const float* z    = (const float*)d_in[7];
    const float* W1   = (const float*)d_in[8];
    const float* W2   = (const float*)d_in[9];
    const float* W3   = (const float*)d_in[10];
    const float* W4   = (const float*)d_in[11];
    const float* W5   = (const float*)d_in[12];

    const int E = in_sizes[1];
    const int N = in_sizes[7] / 10;   // 50000
    const int NCH = (N + SCAN_CHUNK - 1) / SCAN_CHUNK;

    ushort* Abf    = (ushort*)d_ws;                     // [N,512] bf16
    ushort* Sbf    = Abf + (size_t)N * 512;             // [N,512] bf16
    ushort* Wt     = Sbf + (size_t)N * 512;             // [2048,512] bf16 (W1/W2/W3 in turn)
    float*  sup4   = (float*)(Wt + 2048 * 512);         // [N,10] f32
    float*  sup5   = sup4 + (size_t)N * 10;             // [N,10] f32
    int2*   edges  = (int2*)(sup5 + (size_t)N * 10);    // [E]
    int*    rowptr = (int*)(edges + E);                 // [N+1]
    int*    cnt    = rowptr + (N + 1);                  // [N]
    int*    csum   = cnt + N;                           // [NCH]
    float*  out    = (float*)d_out;

    dim3 blk(256);

    // ---- CSR build ----
    hipMemsetAsync(cnt, 0, (size_t)N * sizeof(int), stream);
    csr_count<<<(E + 255) / 256, blk, 0, stream>>>(ar, cnt, E);
    scan1<<<NCH, blk, 0, stream>>>(cnt, csum, N);
    scan2<<<1, 64, 0, stream>>>(csum, NCH);
    scan3<<<NCH, blk, 0, stream>>>(cnt, csum, rowptr, N, E);
    hipMemcpyAsync(cnt, rowptr, (size_t)N * sizeof(int), hipMemcpyDeviceToDevice, stream);
    csr_fill<<<(E + 255) / 256, blk, 0, stream>>>(ar, ac, av, cnt, edges, E);
    hipMemsetAsync(sup4, 0, (size_t)N * 10 * sizeof(float), stream);

    const int spmm_blocks   = (N * 64 + 255) / 256;
    const int spmm10_blocks = (N * 16 + 255) / 256;

    // ---- Layer 1: Abf = bf16(x); Sbf = Abf@W1t; Abf = mix(spmm(Sbf), tra1)
    cvt4<<<(int)(((long)N * 512 / 4 + 255) / 256), blk, 0, stream>>>(x, Abf, (long)N * 512 / 4);
    cvt_wt<<<(512 * 512 + 255) / 256, blk, 0, stream>>>(W1, Wt, 512, 500, 512);
    {
        dim3 g(4, (N + BM - 1) / BM);
        gemm_sup<<<g, blk, 0, stream>>>(Abf, Wt, Sbf, N);
    }
    spmm_bf<<<spmm_blocks, blk, 0, stream>>>(rowptr, edges, Sbf, tra1, Abf, N, 1);

    // ---- Layer 2: Sbf = Abf@W2t; Abf(m2) = mix(spmm(Sbf), tra2)
    cvt_wt<<<(512 * 512 + 255) / 256, blk, 0, stream>>>(W2, Wt, 500, 500, 512);
    {
        dim3 g(4, (N + BM - 1) / BM);
        gemm_sup<<<g, blk, 0, stream>>>(Abf, Wt, Sbf, N);
    }
    spmm_bf<<<spmm_blocks, blk, 0, stream>>>(rowptr, edges, Sbf, tra2, Abf, N, 1);

    // ---- Layer 3 (spmm-first, fully fused): Sbf(g) = spmm(m2) raw;
    //      sup4 = mix(relu(g@W3), tra3) @ W4   (single kernel, atomic partials)
    spmm_bf<<<spmm_blocks, blk, 0, stream>>>(rowptr, edges, Abf, nullptr, Sbf, N, 0);
    cvt_wt<<<(2048 * 512 + 255) / 256, blk, 0, stream>>>(W3, Wt, 500, 2000, 2048);
    {
        dim3 g(16, (N + BM - 1) / BM);
        gemm3_w4<<<g, blk, 0, stream>>>(Sbf, Wt, tra3, W4, sup4, N);
    }

    // ---- Layer 4+5a: sup5 = (mix(spmm(sup4), z)) @ W5  (fused epilogue)
    spmm10<<<spmm10_blocks, blk, 0, stream>>>(rowptr, edges, sup4, z, W5, sup5, N);

    // ---- Layer 5b: out = spmm(sup5) raw
    spmm10<<<spmm10_blocks, blk, 0, stream>>>(rowptr, edges, sup5, nullptr, nullptr, out, N);
}

// Round 6
// 1605.643 us; speedup vs baseline: 22.9037x; 1.0398x over previous
//
#include <hip/hip_runtime.h>
#include <hip/hip_bf16.h>

// GNN: 5-layer GCN on MI355X. Round 6: T2 XOR-swizzle on all MFMA-GEMM LDS tiles.
// - Stage-1 LDS tiles ([row][64] ushorts, 128B stride) were a 16-way bank conflict on
//   ds_read_b128 (SQ_LDS_BANK_CONFLICT 4.06e7 on gemm3_w4). Fix per rule #21:
//   global_load_lds writes linearly -> pre-swizzle the GLOBAL source chunk
//   (acol = ((l&7)^(l>>3))*8) and XOR the same key (row&7) into every ds_read chunk.
// - gemm3_w4: W4 B-frag now in registers (no W4S LDS); act tile stride 128 + swizzle
//   (pad removed) -> LDS exactly 32 KB overlaying As/Bs.
// - Layer 3 fused: act = mix(relu(g@W3), tra3) in regs -> LDS -> @W4 -> atomic sup4.
// - SpMM: CSR gather (on-device counting sort), bf16 [N,512] rows, wave/row.

#define SCAN_CHUNK 512
#define BM 128
#define BN 128
#define BK 64

typedef __attribute__((ext_vector_type(4))) float f32x4;
typedef __attribute__((ext_vector_type(8))) __bf16 bf16x8;
typedef __attribute__((ext_vector_type(8))) short s16x8;

__device__ __forceinline__ bf16x8 as_bf(s16x8 v) { union { s16x8 s; bf16x8 b; } u; u.s = v; return u.b; }
__device__ __forceinline__ ushort f2bf(float f) {
    uint u = __float_as_uint(f);
    return (ushort)((u + 0x7FFFu + ((u >> 16) & 1u)) >> 16);   // RNE
}
__device__ __forceinline__ float bf2f(ushort s) { return __uint_as_float(((uint)s) << 16); }

#define GLL16(g, l)                                                                 \
    __builtin_amdgcn_global_load_lds((const __attribute__((address_space(1))) void*)(g), \
                                     (__attribute__((address_space(3))) void*)(l), 16, 0, 0)

// ---------------- support GEMM: C[M,512]bf16 = A[M,512]bf16 @ Bt[512,512]bf16^T ------
__global__ __launch_bounds__(256) void gemm_sup(const ushort* __restrict__ A,
                                                const ushort* __restrict__ Bt,
                                                ushort* __restrict__ C, int M) {
    __shared__ ushort As[BM * BK];
    __shared__ ushort Bs[BN * BK];
    int tid = threadIdx.x;
    int w = tid >> 6, l = tid & 63;
    int row0 = blockIdx.y * BM, col0 = blockIdx.x * BN;
    int wr = (w >> 1) * 64, wc = (w & 1) * 64;
    f32x4 acc[4][4] = {};
    int arow_off = w * 8 + (l >> 3);
    int acol = (((l & 7) ^ (l >> 3)) << 3);   // swizzled global source chunk
    for (int k0 = 0; k0 < 512; k0 += BK) {
        __syncthreads();
#pragma unroll
        for (int i = 0; i < 4; ++i) {
            int ar = row0 + arow_off + i * 32;
            if (ar >= M) ar = M - 1;
            GLL16(A + (size_t)ar * 512 + k0 + acol, &As[(w * 8 + i * 32) * BK]);
            GLL16(Bt + (size_t)(col0 + arow_off + i * 32) * 512 + k0 + acol, &Bs[(w * 8 + i * 32) * BK]);
        }
        __syncthreads();
#pragma unroll
        for (int s = 0; s < 2; ++s) {
            int cswz = (((s * 4 + (l >> 4)) ^ (l & 7)) << 3);   // swizzled read chunk
            bf16x8 af[4], bfr[4];
#pragma unroll
            for (int m = 0; m < 4; ++m)
                af[m] = as_bf(*(const s16x8*)&As[(wr + m * 16 + (l & 15)) * BK + cswz]);
#pragma unroll
            for (int n = 0; n < 4; ++n)
                bfr[n] = as_bf(*(const s16x8*)&Bs[(wc + n * 16 + (l & 15)) * BK + cswz]);
#pragma unroll
            for (int m = 0; m < 4; ++m)
#pragma unroll
                for (int n = 0; n < 4; ++n)
                    acc[m][n] = __builtin_amdgcn_mfma_f32_16x16x32_bf16(af[m], bfr[n], acc[m][n], 0, 0, 0);
        }
    }
    int crow = (l >> 4) * 4, ccol = l & 15;
#pragma unroll
    for (int m = 0; m < 4; ++m)
#pragma unroll
        for (int n = 0; n < 4; ++n) {
            int gc = col0 + wc + n * 16 + ccol;
#pragma unroll
            for (int r = 0; r < 4; ++r) {
                int gr = row0 + wr + m * 16 + crow + r;
                if (gr < M) C[(size_t)gr * 512 + gc] = f2bf(acc[m][n][r]);
            }
        }
}

// ---------------- fused layer-3: sup4 += (mix(relu(g@W3), tra3)) @ W4 ----------------
// A: g [M,512] bf16. Bt: Wt3 [2048,512] bf16 (pad rows zero). T: tra3 [M,2000] f32.
// W4: [2000,10] f32 (B-frag in registers). sup4: [M,10] f32 (pre-zeroed, atomic).
__global__ __launch_bounds__(256) void gemm3_w4(const ushort* __restrict__ A,
                                                const ushort* __restrict__ Bt,
                                                const float* __restrict__ T,
                                                const float* __restrict__ W4,
                                                float* __restrict__ sup4, int M) {
    __shared__ ushort lds[16384];          // 32 KB
    ushort* As   = lds;                    // [128*64] main loop
    ushort* Bs   = lds + 8192;             // [128*64]
    ushort* actS = lds;                    // [128][128] swizzled, epilogue overlay
    int tid = threadIdx.x;
    int w = tid >> 6, l = tid & 63;
    int row0 = blockIdx.y * BM, col0 = blockIdx.x * BN;
    int wr = (w >> 1) * 64, wc = (w & 1) * 64;
    int crow = (l >> 4) * 4, ccol = l & 15;

    // W4 B-fragment into registers: lane holds W4[col0+wc+s*32+(l>>4)*8 + kk][ccol]
    bf16x8 w4f[2];
    {
#pragma unroll
        for (int s = 0; s < 2; ++s) {
            s16x8 tmp;
#pragma unroll
            for (int kk = 0; kk < 8; ++kk) {
                int gk = col0 + wc + s * 32 + ((l >> 4) << 3) + kk;
                float v = (ccol < 10 && gk < 2000) ? W4[(size_t)gk * 10 + ccol] : 0.f;
                tmp[kk] = (short)f2bf(v);
            }
            w4f[s] = as_bf(tmp);
        }
    }

    f32x4 acc[4][4] = {};
    int arow_off = w * 8 + (l >> 3);
    int acol = (((l & 7) ^ (l >> 3)) << 3);
    for (int k0 = 0; k0 < 512; k0 += BK) {
        __syncthreads();
#pragma unroll
        for (int i = 0; i < 4; ++i) {
            int ar = row0 + arow_off + i * 32;
            if (ar >= M) ar = M - 1;
            GLL16(A + (size_t)ar * 512 + k0 + acol, &As[(w * 8 + i * 32) * BK]);
            GLL16(Bt + (size_t)(col0 + arow_off + i * 32) * 512 + k0 + acol, &Bs[(w * 8 + i * 32) * BK]);
        }
        __syncthreads();
#pragma unroll
        for (int s = 0; s < 2; ++s) {
            int cswz = (((s * 4 + (l >> 4)) ^ (l & 7)) << 3);
            bf16x8 af[4], bfr[4];
#pragma unroll
            for (int m = 0; m < 4; ++m)
                af[m] = as_bf(*(const s16x8*)&As[(wr + m * 16 + (l & 15)) * BK + cswz]);
#pragma unroll
            for (int n = 0; n < 4; ++n)
                bfr[n] = as_bf(*(const s16x8*)&Bs[(wc + n * 16 + (l & 15)) * BK + cswz]);
#pragma unroll
            for (int m = 0; m < 4; ++m)
#pragma unroll
                for (int n = 0; n < 4; ++n)
                    acc[m][n] = __builtin_amdgcn_mfma_f32_16x16x32_bf16(af[m], bfr[n], acc[m][n], 0, 0, 0);
        }
    }

    // epilogue: act tile (mix applied) -> LDS bf16, stride 128, same XOR swizzle
    __syncthreads();
#pragma unroll
    for (int m = 0; m < 4; ++m)
#pragma unroll
        for (int n = 0; n < 4; ++n) {
            int cl = wc + n * 16 + ccol;
            int cch = cl >> 3, clo = cl & 7;
            int gc = col0 + cl;
#pragma unroll
            for (int r = 0; r < 4; ++r) {
                int rl = wr + m * 16 + crow + r;
                int gr = row0 + rl;
                float v = 0.f;
                if (gr < M && gc < 2000)
                    v = 0.5f * fmaxf(acc[m][n][r], 0.f) + 0.5f * T[(size_t)gr * 2000 + gc];
                actS[rl * 128 + (((cch ^ (rl & 7)) << 3) | clo)] = f2bf(v);
            }
        }
    __syncthreads();

    // stage 2: act[128r x 128k] @ W4-frag; each wave: its 64 rows x its 64-k half
    f32x4 acc2[4] = {};
#pragma unroll
    for (int s = 0; s < 2; ++s) {
        int chunk = (wc + s * 32 + ((l >> 4) << 3)) >> 3;
#pragma unroll
        for (int m = 0; m < 4; ++m) {
            int row = wr + m * 16 + ccol;
            bf16x8 af = as_bf(*(const s16x8*)&actS[row * 128 + ((chunk ^ (row & 7)) << 3)]);
            acc2[m] = __builtin_amdgcn_mfma_f32_16x16x32_bf16(af, w4f[s], acc2[m], 0, 0, 0);
        }
    }
    if (ccol < 10) {
#pragma unroll
        for (int m = 0; m < 4; ++m)
#pragma unroll
            for (int r = 0; r < 4; ++r) {
                int gr = row0 + wr + m * 16 + crow + r;
                if (gr < M) atomicAdd(&sup4[(size_t)gr * 10 + ccol], acc2[m][r]);
            }
    }
}

// ---------------- conversions ----------------
__global__ __launch_bounds__(256) void cvt4(const float* __restrict__ s,
                                            ushort* __restrict__ d, long n4) {
    long i = (long)blockIdx.x * 256 + threadIdx.x;
    if (i >= n4) return;
    float4 v = ((const float4*)s)[i];
    ushort4 o = { f2bf(v.x), f2bf(v.y), f2bf(v.z), f2bf(v.w) };
    ((ushort4*)d)[i] = o;
}

// Wt[n][k] (Npad x 512) = bf16(W[k][n]), zero-padded
__global__ __launch_bounds__(256) void cvt_wt(const float* __restrict__ W,
                                              ushort* __restrict__ Wt,
                                              int Ksrc, int Nsrc, int Npad) {
    int i = blockIdx.x * 256 + threadIdx.x;
    if (i >= Npad * 512) return;
    int n = i >> 9, k = i & 511;
    float v = (k < Ksrc && n < Nsrc) ? W[(size_t)k * Nsrc + n] : 0.f;
    Wt[i] = f2bf(v);
}

// ---------------- CSR build: count / scan / fill ----------------
__global__ __launch_bounds__(256) void csr_count(const int* __restrict__ rows,
                                                 int* __restrict__ cnt, int E) {
    int e = blockIdx.x * 256 + threadIdx.x;
    if (e < E) atomicAdd(&cnt[rows[e]], 1);
}

__global__ __launch_bounds__(256) void scan1(const int* __restrict__ cnt,
                                             int* __restrict__ csum, int n) {
    __shared__ int red[256];
    int base = blockIdx.x * SCAN_CHUNK;
    int t = threadIdx.x;
    int s = 0;
    if (base + t < n) s += cnt[base + t];
    if (base + t + 256 < n) s += cnt[base + t + 256];
    red[t] = s;
    __syncthreads();
    for (int off = 128; off; off >>= 1) {
        if (t < off) red[t] += red[t + off];
        __syncthreads();
    }
    if (t == 0) csum[blockIdx.x] = red[0];
}

__global__ void scan2(int* csum, int nch) {
    if (threadIdx.x == 0 && blockIdx.x == 0) {
        int acc = 0;
        for (int i = 0; i < nch; ++i) { int v = csum[i]; csum[i] = acc; acc += v; }
    }
}

__global__ __launch_bounds__(256) void scan3(const int* __restrict__ cnt,
                                             const int* __restrict__ csum,
                                             int* __restrict__ rowptr, int n, int E) {
    __shared__ int sm[SCAN_CHUNK];
    int base = blockIdx.x * SCAN_CHUNK;
    int t = threadIdx.x;
    for (int i = t; i < SCAN_CHUNK; i += 256) sm[i] = (base + i < n) ? cnt[base + i] : 0;
    __syncthreads();
    for (int off = 1; off < SCAN_CHUNK; off <<= 1) {
        int i0 = t, i1 = t + 256;
        int v0 = (i0 >= off) ? sm[i0 - off] : 0;
        int v1 = (i1 >= off) ? sm[i1 - off] : 0;
        __syncthreads();
        sm[i0] += v0;
        sm[i1] += v1;
        __syncthreads();
    }
    int off0 = csum[blockIdx.x];
    for (int i = t; i < SCAN_CHUNK; i += 256)
        if (base + i < n) rowptr[base + i] = off0 + (i ? sm[i - 1] : 0);
    if (blockIdx.x == 0 && t == 0) rowptr[n] = E;
}

__global__ __launch_bounds__(256) void csr_fill(const int* __restrict__ rows,
                                                const int* __restrict__ cols,
                                                const float* __restrict__ vals,
                                                int* __restrict__ cur,
                                                int2* __restrict__ edges, int E) {
    int e = blockIdx.x * 256 + threadIdx.x;
    if (e >= E) return;
    int p = atomicAdd(&cur[rows[e]], 1);
    edges[p] = make_int2(cols[e], __float_as_int(vals[e]));
}

// ---------------- SpMM gather, bf16 source [nrows,512]: wave per row ----------------
__global__ __launch_bounds__(256) void spmm_bf(const int* __restrict__ rowptr,
                                               const int2* __restrict__ edges,
                                               const ushort* __restrict__ S,
                                               const float* __restrict__ T,
                                               ushort* __restrict__ O,
                                               int nrows, int domix) {
    int wid = (int)((blockIdx.x * 256 + threadIdx.x) >> 6);
    int lane = threadIdx.x & 63;
    if (wid >= nrows) return;
    int beg = rowptr[wid], end = rowptr[wid + 1];
    float acc[8] = {0.f, 0.f, 0.f, 0.f, 0.f, 0.f, 0.f, 0.f};
    int e = beg;
    for (; e + 1 < end; e += 2) {
        int2 e0 = edges[e], e1 = edges[e + 1];
        float va = __int_as_float(e0.y), vb = __int_as_float(e1.y);
        s16x8 a = ((const s16x8*)(S + (size_t)e0.x * 512))[lane];
        s16x8 b = ((const s16x8*)(S + (size_t)e1.x * 512))[lane];
#pragma unroll
        for (int j = 0; j < 8; ++j)
            acc[j] += va * bf2f((ushort)a[j]) + vb * bf2f((ushort)b[j]);
    }
    if (e < end) {
        int2 e0 = edges[e];
        float va = __int_as_float(e0.y);
        s16x8 a = ((const s16x8*)(S + (size_t)e0.x * 512))[lane];
#pragma unroll
        for (int j = 0; j < 8; ++j)
            acc[j] += va * bf2f((ushort)a[j]);
    }
    int c0 = lane * 8;
    float res[8];
    if (domix) {
        float tv[8] = {0.f, 0.f, 0.f, 0.f, 0.f, 0.f, 0.f, 0.f};
        const float* trow = T + (size_t)wid * 500;
        if (c0 + 8 <= 500) {
            float4 t0 = *(const float4*)(trow + c0);
            float4 t1 = *(const float4*)(trow + c0 + 4);
            tv[0] = t0.x; tv[1] = t0.y; tv[2] = t0.z; tv[3] = t0.w;
            tv[4] = t1.x; tv[5] = t1.y; tv[6] = t1.z; tv[7] = t1.w;
        } else {
#pragma unroll
            for (int j = 0; j < 8; ++j)
                if (c0 + j < 500) tv[j] = trow[c0 + j];
        }
#pragma unroll
        for (int j = 0; j < 8; ++j)
            res[j] = (c0 + j < 500) ? (0.5f * fmaxf(acc[j], 0.f) + 0.5f * tv[j]) : 0.f;
    } else {
#pragma unroll
        for (int j = 0; j < 8; ++j)
            res[j] = (c0 + j < 500) ? acc[j] : 0.f;
    }
    s16x8 o;
#pragma unroll
    for (int j = 0; j < 8; ++j) o[j] = (short)f2bf(res[j]);
    ((s16x8*)(O + (size_t)wid * 512))[lane] = o;
}

// ---------------- SpMM gather, D=10 f32; optional fused mix+@W5 epilogue -------------
__global__ __launch_bounds__(256) void spmm10(const int* __restrict__ rowptr,
                                              const int2* __restrict__ edges,
                                              const float* __restrict__ S,
                                              const float* __restrict__ T,
                                              const float* __restrict__ W5,
                                              float* __restrict__ O, int nrows) {
    int g = (int)((blockIdx.x * 256 + threadIdx.x) >> 4);
    int t = threadIdx.x & 15;
    if (g >= nrows || t >= 10) return;
    int beg = rowptr[g], end = rowptr[g + 1];
    float acc = 0.f;
    for (int e = beg; e < end; ++e) {
        int2 ed = edges[e];
        acc += __int_as_float(ed.y) * S[(size_t)ed.x * 10 + t];
    }
    if (W5) {
        float m = 0.5f * fmaxf(acc, 0.f) + 0.5f * T[(size_t)g * 10 + t];
        float s5 = 0.f;
#pragma unroll
        for (int i = 0; i < 10; ++i)
            s5 += __shfl(m, i, 16) * W5[i * 10 + t];
        O[(size_t)g * 10 + t] = s5;
    } else {
        O[(size_t)g * 10 + t] = acc;
    }
}

extern "C" void kernel_launch(void* const* d_in, const int* in_sizes, int n_in,
                              void* d_out, int out_size, void* d_ws, size_t ws_size,
                              hipStream_t stream) {
    const float* x    = (const float*)d_in[0];
    const int*   ar   = (const int*)d_in[1];
    const int*   ac   = (const int*)d_in[2];
    const float* av   = (const float*)d_in[3];
    const float* tra1 = (const float*)d_in[4];
    const float* tra2 = (const float*)d_in[5];
    const float* tra3 = (const float*)d_in[6];
    const float* z    = (const float*)d_in[7];
    const float* W1   = (const float*)d_in[8];
    const float* W2   = (const float*)d_in[9];
    const float* W3   = (const float*)d_in[10];
    const float* W4   = (const float*)d_in[11];
    const float* W5   = (const float*)d_in[12];

    const int E = in_sizes[1];
    const int N = in_sizes[7] / 10;   // 50000
    const int NCH = (N + SCAN_CHUNK - 1) / SCAN_CHUNK;

    ushort* Abf    = (ushort*)d_ws;                     // [N,512] bf16
    ushort* Sbf    = Abf + (size_t)N * 512;             // [N,512] bf16
    ushort* Wt     = Sbf + (size_t)N * 512;             // [2048,512] bf16 (W1/W2/W3 in turn)
    float*  sup4   = (float*)(Wt + 2048 * 512);         // [N,10] f32
    float*  sup5   = sup4 + (size_t)N * 10;             // [N,10] f32
    int2*   edges  = (int2*)(sup5 + (size_t)N * 10);    // [E]
    int*    rowptr = (int*)(edges + E);                 // [N+1]
    int*    cnt    = rowptr + (N + 1);                  // [N]
    int*    csum   = cnt + N;                           // [NCH]
    float*  out    = (float*)d_out;

    dim3 blk(256);

    // ---- CSR build ----
    hipMemsetAsync(cnt, 0, (size_t)N * sizeof(int), stream);
    csr_count<<<(E + 255) / 256, blk, 0, stream>>>(ar, cnt, E);
    scan1<<<NCH, blk, 0, stream>>>(cnt, csum, N);
    scan2<<<1, 64, 0, stream>>>(csum, NCH);
    scan3<<<NCH, blk, 0, stream>>>(cnt, csum, rowptr, N, E);
    hipMemcpyAsync(cnt, rowptr, (size_t)N * sizeof(int), hipMemcpyDeviceToDevice, stream);
    csr_fill<<<(E + 255) / 256, blk, 0, stream>>>(ar, ac, av, cnt, edges, E);
    hipMemsetAsync(sup4, 0, (size_t)N * 10 * sizeof(float), stream);

    const int spmm_blocks   = (N * 64 + 255) / 256;
    const int spmm10_blocks = (N * 16 + 255) / 256;

    // ---- Layer 1: Abf = bf16(x); Sbf = Abf@W1t; Abf = mix(spmm(Sbf), tra1)
    cvt4<<<(int)(((long)N * 512 / 4 + 255) / 256), blk, 0, stream>>>(x, Abf, (long)N * 512 / 4);
    cvt_wt<<<(512 * 512 + 255) / 256, blk, 0, stream>>>(W1, Wt, 512, 500, 512);
    {
        dim3 g(4, (N + BM - 1) / BM);
        gemm_sup<<<g, blk, 0, stream>>>(Abf, Wt, Sbf, N);
    }
    spmm_bf<<<spmm_blocks, blk, 0, stream>>>(rowptr, edges, Sbf, tra1, Abf, N, 1);

    // ---- Layer 2: Sbf = Abf@W2t; Abf(m2) = mix(spmm(Sbf), tra2)
    cvt_wt<<<(512 * 512 + 255) / 256, blk, 0, stream>>>(W2, Wt, 500, 500, 512);
    {
        dim3 g(4, (N + BM - 1) / BM);
        gemm_sup<<<g, blk, 0, stream>>>(Abf, Wt, Sbf, N);
    }
    spmm_bf<<<spmm_blocks, blk, 0, stream>>>(rowptr, edges, Sbf, tra2, Abf, N, 1);

    // ---- Layer 3 (spmm-first, fully fused): Sbf(g) = spmm(m2) raw;
    //      sup4 = mix(relu(g@W3), tra3) @ W4   (single kernel, atomic partials)
    spmm_bf<<<spmm_blocks, blk, 0, stream>>>(rowptr, edges, Abf, nullptr, Sbf, N, 0);
    cvt_wt<<<(2048 * 512 + 255) / 256, blk, 0, stream>>>(W3, Wt, 500, 2000, 2048);
    {
        dim3 g(16, (N + BM - 1) / BM);
        gemm3_w4<<<g, blk, 0, stream>>>(Sbf, Wt, tra3, W4, sup4, N);
    }

    // ---- Layer 4+5a: sup5 = (mix(spmm(sup4), z)) @ W5  (fused epilogue)
    spmm10<<<spmm10_blocks, blk, 0, stream>>>(rowptr, edges, sup4, z, W5, sup5, N);

    // ---- Layer 5b: out = spmm(sup5) raw
    spmm10<<<spmm10_blocks, blk, 0, stream>>>(rowptr, edges, sup5, nullptr, nullptr, out, N);
}